// Round 1
// baseline (1970.808 us; speedup 1.0000x reference)
//
#include <hip/hip_runtime.h>
#include <stdint.h>

#define BATCH 4
#define SEQ 2048
#define DMODEL 1024
#define NHEADS 16
#define HDIM 64

typedef __attribute__((ext_vector_type(4))) short short4v;
typedef __attribute__((ext_vector_type(4))) float float4v;
typedef __attribute__((ext_vector_type(4))) unsigned int uint4v;
typedef __attribute__((ext_vector_type(4))) unsigned short ushort4v;
typedef __attribute__((ext_vector_type(8))) __bf16 bf16x8;

union FragAB { short4v h[2]; bf16x8 v; };

__device__ __forceinline__ float bf2f(unsigned short u){
  union { unsigned int i; float f; } v; v.i = ((unsigned int)u) << 16; return v.f;
}
__device__ __forceinline__ unsigned short f2bf(float f){
  union { unsigned int i; float f; } v; v.f = f;
  unsigned int x = v.i;
  return (unsigned short)((x + 0x7FFFu + ((x >> 16) & 1u)) >> 16);
}

// ---------------- fp32 -> bf16 conversion (vector x4) ----------------
__global__ void cvt_f32_bf16(const float* __restrict__ in, unsigned short* __restrict__ out, int n4){
  int i = blockIdx.x * 256 + threadIdx.x;
  if (i < n4){
    float4v f = ((const float4v*)in)[i];
    ushort4v o;
    o[0]=f2bf(f[0]); o[1]=f2bf(f[1]); o[2]=f2bf(f[2]); o[3]=f2bf(f[3]);
    ((ushort4v*)out)[i] = o;
  }
}

// ---------------- bf16 GEMM: C[m][n] = sum_k A[m][k]*W[n][k] ----------------
// mode 0: scatter bf16 to [B][H][S][HDIM]   mode 1: write fp32 to out[m*DMODEL+n]
__launch_bounds__(256)
__global__ void gemm_bt(const unsigned short* __restrict__ A,
                        const unsigned short* __restrict__ W,
                        void* __restrict__ out, int mode)
{
  __shared__ unsigned short Alds[64][40];   // +8 pad, keeps 16B alignment (80B stride)
  __shared__ unsigned short Blds[64][40];

  const int tid  = threadIdx.x;
  const int m0   = blockIdx.y * 64;
  const int n0   = blockIdx.x * 64;
  const int wid  = tid >> 6, lane = tid & 63;
  const int wm   = wid >> 1, wn = wid & 1;
  const int lg   = lane >> 4, lr = lane & 15;
  const int srow = tid >> 2, scol = (tid & 3) * 8;

  float4v acc[2][2] = {};

  for (int k0 = 0; k0 < DMODEL; k0 += 32){
    *(uint4v*)&Alds[srow][scol] = *(const uint4v*)(A + (size_t)(m0 + srow) * DMODEL + k0 + scol);
    *(uint4v*)&Blds[srow][scol] = *(const uint4v*)(W + (size_t)(n0 + srow) * DMODEL + k0 + scol);
    __syncthreads();

    FragAB bfr[2];
    #pragma unroll
    for (int fn = 0; fn < 2; ++fn){
      const unsigned short* brow = &Blds[wn*32 + fn*16 + lr][0];
      bfr[fn].h[0] = *(const short4v*)(brow + lg*4);
      bfr[fn].h[1] = *(const short4v*)(brow + 16 + lg*4);
    }
    #pragma unroll
    for (int fm = 0; fm < 2; ++fm){
      const unsigned short* arow = &Alds[wm*32 + fm*16 + lr][0];
      FragAB afr;
      afr.h[0] = *(const short4v*)(arow + lg*4);
      afr.h[1] = *(const short4v*)(arow + 16 + lg*4);
      #pragma unroll
      for (int fn = 0; fn < 2; ++fn){
        acc[fm][fn] = __builtin_amdgcn_mfma_f32_16x16x32_bf16(afr.v, bfr[fn].v, acc[fm][fn], 0, 0, 0);
      }
    }
    __syncthreads();
  }

  #pragma unroll
  for (int fm = 0; fm < 2; ++fm)
    #pragma unroll
    for (int fn = 0; fn < 2; ++fn)
      #pragma unroll
      for (int r = 0; r < 4; ++r){
        int gm = m0 + wm*32 + fm*16 + lg*4 + r;   // D row = M index
        int gn = n0 + wn*32 + fn*16 + lr;         // D col = N index
        float vv = acc[fm][fn][r];
        if (mode == 0){
          int b = gm >> 11, s = gm & (SEQ - 1);
          int h = gn >> 6,  d = gn & (HDIM - 1);
          ((unsigned short*)out)[(((size_t)(b*NHEADS + h))*SEQ + s)*HDIM + d] = f2bf(vv);
        } else {
          ((float*)out)[(size_t)gm * DMODEL + gn] = vv;
        }
      }
}

// ---------------- RoPE in-place on [B][H][S][HDIM] bf16 ----------------
__global__ void rope_kernel(unsigned short* __restrict__ T, const int* __restrict__ pos){
  int idx = blockIdx.x * 256 + threadIdx.x;        // B*H*S*32 threads
  if (idx >= BATCH*NHEADS*SEQ*32) return;
  int i  = idx & 31;
  int s  = (idx >> 5) & (SEQ - 1);
  int bh = idx >> 16;
  unsigned short* p = T + ((size_t)bh * SEQ + s) * HDIM + 2*i;
  float e = bf2f(p[0]), o = bf2f(p[1]);
  // theta^(-2i/64) = 2^(-i * 2*log2(10000)/64)
  float inv = exp2f(-0.41524101186092030f * (float)i);
  float ang = (float)pos[s] * inv;
  float sn = sinf(ang), cs = cosf(ang);
  p[0] = f2bf(e*cs - o*sn);
  p[1] = f2bf(e*sn + o*cs);
}

// ---------------- causal flash attention (fp32 VALU), Dh=64 ----------------
// grid (8, 64): x = q-tile of 256 rows, y = b*NHEADS+h. 1 thread = 1 q row.
__launch_bounds__(256, 2)
__global__ void flash_attn(const unsigned short* __restrict__ Qg,
                           const unsigned short* __restrict__ Kg,
                           const unsigned short* __restrict__ Vg,
                           unsigned short* __restrict__ Og)
{
  __shared__ float Klds[64][68];
  __shared__ float Vlds[64][68];

  const int tid = threadIdx.x;
  const int qt  = blockIdx.x;
  const int bh  = blockIdx.y;
  const int r   = qt * 256 + tid;
  const size_t base = (size_t)bh * SEQ * HDIM;

  float q[64];
  {
    const uint4v* qp = (const uint4v*)(Qg + base + (size_t)r * HDIM);
    #pragma unroll
    for (int c8 = 0; c8 < 8; ++c8){
      uint4v u = qp[c8];
      #pragma unroll
      for (int w2 = 0; w2 < 4; ++w2){
        unsigned int x = u[w2];
        q[c8*8 + w2*2]     = bf2f((unsigned short)(x & 0xffffu)) * 0.125f;
        q[c8*8 + w2*2 + 1] = bf2f((unsigned short)(x >> 16)) * 0.125f;
      }
    }
  }
  float acc[64];
  #pragma unroll
  for (int d = 0; d < 64; ++d) acc[d] = 0.f;
  float mrun = -INFINITY, lrun = 0.f;

  const int ntiles = qt * 4 + 4;
  const int srow = tid >> 2, scg = tid & 3;

  for (int t = 0; t < ntiles; ++t){
    const int kv0 = t * 64;
    {
      const uint4v* ks = (const uint4v*)(Kg + base + (size_t)(kv0 + srow) * HDIM + scg*16);
      const uint4v* vs = (const uint4v*)(Vg + base + (size_t)(kv0 + srow) * HDIM + scg*16);
      uint4v ka = ks[0], kb = ks[1], va = vs[0], vb = vs[1];
      float* kd = &Klds[srow][scg*16];
      float* vd = &Vlds[srow][scg*16];
      #pragma unroll
      for (int j = 0; j < 4; ++j){
        kd[2*j]     = bf2f((unsigned short)(ka[j] & 0xffffu));
        kd[2*j + 1] = bf2f((unsigned short)(ka[j] >> 16));
        kd[8 + 2*j]     = bf2f((unsigned short)(kb[j] & 0xffffu));
        kd[8 + 2*j + 1] = bf2f((unsigned short)(kb[j] >> 16));
        vd[2*j]     = bf2f((unsigned short)(va[j] & 0xffffu));
        vd[2*j + 1] = bf2f((unsigned short)(va[j] >> 16));
        vd[8 + 2*j]     = bf2f((unsigned short)(vb[j] & 0xffffu));
        vd[8 + 2*j + 1] = bf2f((unsigned short)(vb[j] >> 16));
      }
    }
    __syncthreads();

    int kmax = r - kv0; if (kmax > 63) kmax = 63;
    for (int kv = 0; kv <= kmax; ++kv){
      const float4v* kp = (const float4v*)&Klds[kv][0];
      float s = 0.f;
      #pragma unroll
      for (int dq = 0; dq < 16; ++dq){
        float4v kk = kp[dq];
        s += q[dq*4+0]*kk[0] + q[dq*4+1]*kk[1] + q[dq*4+2]*kk[2] + q[dq*4+3]*kk[3];
      }
      if (s > mrun){
        float c = __expf(mrun - s);
        lrun *= c;
        #pragma unroll
        for (int d = 0; d < 64; ++d) acc[d] *= c;
        mrun = s;
      }
      float p = __expf(s - mrun);
      lrun += p;
      const float4v* vp = (const float4v*)&Vlds[kv][0];
      #pragma unroll
      for (int dq = 0; dq < 16; ++dq){
        float4v vv = vp[dq];
        acc[dq*4+0] += p*vv[0]; acc[dq*4+1] += p*vv[1];
        acc[dq*4+2] += p*vv[2]; acc[dq*4+3] += p*vv[3];
      }
    }
    __syncthreads();
  }

  const float inv = 1.0f / lrun;
  const int b = bh >> 4, h = bh & (NHEADS - 1);
  unsigned int* op = (unsigned int*)(Og + ((size_t)(b*SEQ + r)) * DMODEL + h*HDIM);
  #pragma unroll
  for (int d = 0; d < 64; d += 2){
    unsigned int wrd = (unsigned int)f2bf(acc[d]*inv) | ((unsigned int)f2bf(acc[d+1]*inv) << 16);
    op[d >> 1] = wrd;
  }
}

// ---------------- launch ----------------
extern "C" void kernel_launch(void* const* d_in, const int* in_sizes, int n_in,
                              void* d_out, int out_size, void* d_ws, size_t ws_size,
                              hipStream_t stream)
{
  const float* x  = (const float*)d_in[0];
  const float* Wq = (const float*)d_in[1];
  const float* Wk = (const float*)d_in[2];
  const float* Wv = (const float*)d_in[3];
  const float* Wo = (const float*)d_in[4];
  const int* tpos = (const int*)d_in[5];

  char* w = (char*)d_ws;
  const size_t XBF   = 16777216;   // 8192*1024*2
  const size_t WBF   = 2097152;    // 1024*1024*2
  unsigned short* x_bf  = (unsigned short*)(w);
  unsigned short* wq_bf = (unsigned short*)(w + XBF);
  unsigned short* wk_bf = (unsigned short*)(w + XBF + WBF);
  unsigned short* wv_bf = (unsigned short*)(w + XBF + 2*WBF);
  unsigned short* wo_bf = (unsigned short*)(w + XBF + 3*WBF);
  unsigned short* Qb = (unsigned short*)(w + XBF + 4*WBF);
  unsigned short* Kb = (unsigned short*)(w + XBF + 4*WBF + XBF);
  unsigned short* Vb = (unsigned short*)(w + XBF + 4*WBF + 2*XBF);
  unsigned short* Ab = (unsigned short*)(w + XBF + 4*WBF + 3*XBF);

  cvt_f32_bf16<<<8192, 256, 0, stream>>>(x,  x_bf,  2097152);
  cvt_f32_bf16<<<1024, 256, 0, stream>>>(Wq, wq_bf, 262144);
  cvt_f32_bf16<<<1024, 256, 0, stream>>>(Wk, wk_bf, 262144);
  cvt_f32_bf16<<<1024, 256, 0, stream>>>(Wv, wv_bf, 262144);
  cvt_f32_bf16<<<1024, 256, 0, stream>>>(Wo, wo_bf, 262144);

  dim3 gg(16, 128);
  gemm_bt<<<gg, 256, 0, stream>>>(x_bf, wq_bf, Qb, 0);
  gemm_bt<<<gg, 256, 0, stream>>>(x_bf, wk_bf, Kb, 0);
  gemm_bt<<<gg, 256, 0, stream>>>(x_bf, wv_bf, Vb, 0);

  rope_kernel<<<16384, 256, 0, stream>>>(Qb, tpos);
  rope_kernel<<<16384, 256, 0, stream>>>(Kb, tpos);

  flash_attn<<<dim3(8, 64), 256, 0, stream>>>(Qb, Kb, Vb, Ab);

  gemm_bt<<<gg, 256, 0, stream>>>(Ab, wo_bf, d_out, 1);
}

// Round 2
// 508.098 us; speedup vs baseline: 3.8788x; 3.8788x over previous
//
#include <hip/hip_runtime.h>
#include <stdint.h>

#define BATCH 4
#define SEQ 2048
#define DMODEL 1024
#define NHEADS 16
#define HDIM 64

typedef __attribute__((ext_vector_type(4))) short short4v;
typedef __attribute__((ext_vector_type(4))) float float4v;
typedef __attribute__((ext_vector_type(2))) unsigned int uint2v;
typedef __attribute__((ext_vector_type(4))) unsigned int uint4v;
typedef __attribute__((ext_vector_type(4))) unsigned short ushort4v;
typedef __attribute__((ext_vector_type(8))) __bf16 bf16x8;

union FragAB { short4v h[2]; bf16x8 v; };

__device__ __forceinline__ float bf2f(unsigned short u){
  union { unsigned int i; float f; } v; v.i = ((unsigned int)u) << 16; return v.f;
}
__device__ __forceinline__ unsigned short f2bf(float f){
  union { unsigned int i; float f; } v; v.f = f;
  unsigned int x = v.i;
  return (unsigned short)((x + 0x7FFFu + ((x >> 16) & 1u)) >> 16);
}

// ---------------- fp32 -> bf16 conversion (vector x4) ----------------
__global__ void cvt_f32_bf16(const float* __restrict__ in, unsigned short* __restrict__ out, int n4){
  int i = blockIdx.x * 256 + threadIdx.x;
  if (i < n4){
    float4v f = ((const float4v*)in)[i];
    ushort4v o;
    o[0]=f2bf(f[0]); o[1]=f2bf(f[1]); o[2]=f2bf(f[2]); o[3]=f2bf(f[3]);
    ((ushort4v*)out)[i] = o;
  }
}

// ---------------- bf16 GEMM: C[m][n] = sum_k A[m][k]*W[n][k] ----------------
// mode 0: scatter bf16 to [B][H][S][HDIM]   mode 1: write fp32 to out[m*DMODEL+n]
__launch_bounds__(256)
__global__ void gemm_bt(const unsigned short* __restrict__ A,
                        const unsigned short* __restrict__ W,
                        void* __restrict__ out, int mode)
{
  __shared__ unsigned short Alds[64][40];
  __shared__ unsigned short Blds[64][40];

  const int tid  = threadIdx.x;
  const int m0   = blockIdx.y * 64;
  const int n0   = blockIdx.x * 64;
  const int wid  = tid >> 6, lane = tid & 63;
  const int wm   = wid >> 1, wn = wid & 1;
  const int lg   = lane >> 4, lr = lane & 15;
  const int srow = tid >> 2, scol = (tid & 3) * 8;

  float4v acc[2][2] = {};

  for (int k0 = 0; k0 < DMODEL; k0 += 32){
    *(uint4v*)&Alds[srow][scol] = *(const uint4v*)(A + (size_t)(m0 + srow) * DMODEL + k0 + scol);
    *(uint4v*)&Blds[srow][scol] = *(const uint4v*)(W + (size_t)(n0 + srow) * DMODEL + k0 + scol);
    __syncthreads();

    FragAB bfr[2];
    #pragma unroll
    for (int fn = 0; fn < 2; ++fn){
      const unsigned short* brow = &Blds[wn*32 + fn*16 + lr][0];
      bfr[fn].h[0] = *(const short4v*)(brow + lg*4);
      bfr[fn].h[1] = *(const short4v*)(brow + 16 + lg*4);
    }
    #pragma unroll
    for (int fm = 0; fm < 2; ++fm){
      const unsigned short* arow = &Alds[wm*32 + fm*16 + lr][0];
      FragAB afr;
      afr.h[0] = *(const short4v*)(arow + lg*4);
      afr.h[1] = *(const short4v*)(arow + 16 + lg*4);
      #pragma unroll
      for (int fn = 0; fn < 2; ++fn){
        acc[fm][fn] = __builtin_amdgcn_mfma_f32_16x16x32_bf16(afr.v, bfr[fn].v, acc[fm][fn], 0, 0, 0);
      }
    }
    __syncthreads();
  }

  #pragma unroll
  for (int fm = 0; fm < 2; ++fm)
    #pragma unroll
    for (int fn = 0; fn < 2; ++fn)
      #pragma unroll
      for (int r = 0; r < 4; ++r){
        int gm = m0 + wm*32 + fm*16 + lg*4 + r;
        int gn = n0 + wn*32 + fn*16 + lr;
        float vv = acc[fm][fn][r];
        if (mode == 0){
          int b = gm >> 11, s = gm & (SEQ - 1);
          int h = gn >> 6,  d = gn & (HDIM - 1);
          ((unsigned short*)out)[(((size_t)(b*NHEADS + h))*SEQ + s)*HDIM + d] = f2bf(vv);
        } else {
          ((float*)out)[(size_t)gm * DMODEL + gn] = vv;
        }
      }
}

// ---------------- RoPE in-place on [B][H][S][HDIM] bf16 ----------------
__global__ void rope_kernel(unsigned short* __restrict__ T, const int* __restrict__ pos){
  int idx = blockIdx.x * 256 + threadIdx.x;
  if (idx >= BATCH*NHEADS*SEQ*32) return;
  int i  = idx & 31;
  int s  = (idx >> 5) & (SEQ - 1);
  int bh = idx >> 16;
  unsigned short* p = T + ((size_t)bh * SEQ + s) * HDIM + 2*i;
  float e = bf2f(p[0]), o = bf2f(p[1]);
  float inv = exp2f(-0.41524101186092030f * (float)i);
  float ang = (float)pos[s] * inv;
  float sn = sinf(ang), cs = cosf(ang);
  p[0] = f2bf(e*cs - o*sn);
  p[1] = f2bf(e*sn + o*cs);
}

// ---------------- MFMA causal flash attention, Dh=64, swapped-operand ----------------
// grid (32, 64): x = q-tile of 64 rows, y = b*NHEADS+h. 4 waves, 16 q-rows/wave.
// S^T = mfma(K, Q): lane's col (lane&15) = q-row; P stays in registers as the
// B-fragment of PV's  O^T = mfma(V^T, P).
__launch_bounds__(256, 2)
__global__ void flash_attn_mfma(const unsigned short* __restrict__ Qg,
                                const unsigned short* __restrict__ Kg,
                                const unsigned short* __restrict__ Vg,
                                unsigned short* __restrict__ Og)
{
  __shared__ unsigned short Klds[64][72];  // [k][d], pad->2-way max
  __shared__ unsigned short Vt[64][72];    // [d][k] transposed

  const int tid  = threadIdx.x;
  const int w    = tid >> 6;
  const int lane = tid & 63;
  const int lg   = lane >> 4, lr = lane & 15;
  const int qt   = blockIdx.x;
  const int bh   = blockIdx.y;
  const int q0   = qt * 64;
  const size_t base = (size_t)bh * SEQ * HDIM;

  const int qglob = q0 + w*16 + lr;   // this lane's q-row (all its work is this row)

  // Q fragments (B operand): B[kk=d][n=q], lane holds Q[q=lr][d = c*32 + lg*4+j (+16)]
  FragAB qf[2];
  {
    const unsigned short* qrow = Qg + base + (size_t)qglob * HDIM;
    qf[0].h[0] = *(const short4v*)(qrow + lg*4);
    qf[0].h[1] = *(const short4v*)(qrow + 16 + lg*4);
    qf[1].h[0] = *(const short4v*)(qrow + 32 + lg*4);
    qf[1].h[1] = *(const short4v*)(qrow + 48 + lg*4);
  }

  float4v o[4] = {};          // O^T frags: row d = dm*16+lg*4+r, col q = lr
  float mrun = -INFINITY, lrun = 0.f;

  const int ntiles = qt + 1;
  const int sr = tid >> 3;          // staging row 0..31
  const int sc = (tid & 7) * 8;     // staging col (bf16 units)

  for (int t = 0; t < ntiles; ++t){
    const int kv0 = t * 64;
    #pragma unroll
    for (int p = 0; p < 2; ++p){
      int row = p*32 + sr;
      uint4v kvv = *(const uint4v*)(Kg + base + (size_t)(kv0 + row) * HDIM + sc);
      *(uint4v*)&Klds[row][sc] = kvv;
      uint4v vvv = *(const uint4v*)(Vg + base + (size_t)(kv0 + row) * HDIM + sc);
      #pragma unroll
      for (int j = 0; j < 4; ++j){
        unsigned int x = vvv[j];
        Vt[sc + 2*j][row]     = (unsigned short)(x & 0xffffu);
        Vt[sc + 2*j + 1][row] = (unsigned short)(x >> 16);
      }
    }
    __syncthreads();

    // ---- S^T = K * Q  (4 blocks of 16 k-rows) ----
    float p4[4][4];
    #pragma unroll
    for (int kb = 0; kb < 4; ++kb){
      const unsigned short* krow = &Klds[kb*16 + lr][0];
      FragAB kf0, kf1;
      kf0.h[0] = *(const short4v*)(krow + lg*4);
      kf0.h[1] = *(const short4v*)(krow + 16 + lg*4);
      kf1.h[0] = *(const short4v*)(krow + 32 + lg*4);
      kf1.h[1] = *(const short4v*)(krow + 48 + lg*4);
      float4v st = {};
      st = __builtin_amdgcn_mfma_f32_16x16x32_bf16(kf0.v, qf[0].v, st, 0, 0, 0);
      st = __builtin_amdgcn_mfma_f32_16x16x32_bf16(kf1.v, qf[1].v, st, 0, 0, 0);
      #pragma unroll
      for (int r = 0; r < 4; ++r){
        int kglob = kv0 + kb*16 + lg*4 + r;
        float s = st[r] * 0.125f;
        p4[kb][r] = (kglob <= qglob) ? s : -1e30f;
      }
    }

    // ---- online softmax over this tile's 64 keys (row = lane's q) ----
    float rmax = p4[0][0];
    #pragma unroll
    for (int kb = 0; kb < 4; ++kb)
      #pragma unroll
      for (int r = 0; r < 4; ++r) rmax = fmaxf(rmax, p4[kb][r]);
    rmax = fmaxf(rmax, __shfl_xor(rmax, 16));
    rmax = fmaxf(rmax, __shfl_xor(rmax, 32));

    float mnew = fmaxf(mrun, rmax);
    float alpha = __expf(mrun - mnew);
    float rsum = 0.f;
    #pragma unroll
    for (int kb = 0; kb < 4; ++kb)
      #pragma unroll
      for (int r = 0; r < 4; ++r){
        float e = __expf(p4[kb][r] - mnew);
        p4[kb][r] = e;
        rsum += e;
      }
    rsum += __shfl_xor(rsum, 16);
    rsum += __shfl_xor(rsum, 32);
    lrun = lrun * alpha + rsum;
    mrun = mnew;

    #pragma unroll
    for (int dm = 0; dm < 4; ++dm)
      #pragma unroll
      for (int r = 0; r < 4; ++r) o[dm][r] *= alpha;

    // ---- O^T += V^T * P  (2 k-chunks of 32) ----
    #pragma unroll
    for (int kc = 0; kc < 2; ++kc){
      FragAB pf;
      #pragma unroll
      for (int j = 0; j < 4; ++j){
        pf.h[0][j] = (short)f2bf(p4[2*kc][j]);
        pf.h[1][j] = (short)f2bf(p4[2*kc + 1][j]);
      }
      #pragma unroll
      for (int dm = 0; dm < 4; ++dm){
        const unsigned short* vrow = &Vt[dm*16 + lr][0];
        FragAB vf;
        vf.h[0] = *(const short4v*)(vrow + kc*32 + lg*4);
        vf.h[1] = *(const short4v*)(vrow + kc*32 + 16 + lg*4);
        o[dm] = __builtin_amdgcn_mfma_f32_16x16x32_bf16(vf.v, pf.v, o[dm], 0, 0, 0);
      }
    }
    __syncthreads();
  }

  // ---- epilogue: O^T lane (d=dm*16+lg*4+r, q=lr) -> Og[b][s][h*64+d] bf16 ----
  const float inv = 1.0f / lrun;
  const int b = bh >> 4, h = bh & (NHEADS - 1);
  unsigned short* orow = Og + ((size_t)(b*SEQ + qglob)) * DMODEL + h*HDIM;
  #pragma unroll
  for (int dm = 0; dm < 4; ++dm){
    uint2v pkd;
    pkd[0] = (unsigned int)f2bf(o[dm][0]*inv) | ((unsigned int)f2bf(o[dm][1]*inv) << 16);
    pkd[1] = (unsigned int)f2bf(o[dm][2]*inv) | ((unsigned int)f2bf(o[dm][3]*inv) << 16);
    *(uint2v*)(orow + dm*16 + lg*4) = pkd;
  }
}

// ---------------- launch ----------------
extern "C" void kernel_launch(void* const* d_in, const int* in_sizes, int n_in,
                              void* d_out, int out_size, void* d_ws, size_t ws_size,
                              hipStream_t stream)
{
  const float* x  = (const float*)d_in[0];
  const float* Wq = (const float*)d_in[1];
  const float* Wk = (const float*)d_in[2];
  const float* Wv = (const float*)d_in[3];
  const float* Wo = (const float*)d_in[4];
  const int* tpos = (const int*)d_in[5];

  char* w = (char*)d_ws;
  const size_t XBF   = 16777216;   // 8192*1024*2
  const size_t WBF   = 2097152;    // 1024*1024*2
  unsigned short* x_bf  = (unsigned short*)(w);
  unsigned short* wq_bf = (unsigned short*)(w + XBF);
  unsigned short* wk_bf = (unsigned short*)(w + XBF + WBF);
  unsigned short* wv_bf = (unsigned short*)(w + XBF + 2*WBF);
  unsigned short* wo_bf = (unsigned short*)(w + XBF + 3*WBF);
  unsigned short* Qb = (unsigned short*)(w + XBF + 4*WBF);
  unsigned short* Kb = (unsigned short*)(w + XBF + 4*WBF + XBF);
  unsigned short* Vb = (unsigned short*)(w + XBF + 4*WBF + 2*XBF);
  unsigned short* Ab = (unsigned short*)(w + XBF + 4*WBF + 3*XBF);

  cvt_f32_bf16<<<8192, 256, 0, stream>>>(x,  x_bf,  2097152);
  cvt_f32_bf16<<<1024, 256, 0, stream>>>(Wq, wq_bf, 262144);
  cvt_f32_bf16<<<1024, 256, 0, stream>>>(Wk, wk_bf, 262144);
  cvt_f32_bf16<<<1024, 256, 0, stream>>>(Wv, wv_bf, 262144);
  cvt_f32_bf16<<<1024, 256, 0, stream>>>(Wo, wo_bf, 262144);

  dim3 gg(16, 128);
  gemm_bt<<<gg, 256, 0, stream>>>(x_bf, wq_bf, Qb, 0);
  gemm_bt<<<gg, 256, 0, stream>>>(x_bf, wk_bf, Kb, 0);
  gemm_bt<<<gg, 256, 0, stream>>>(x_bf, wv_bf, Vb, 0);

  rope_kernel<<<16384, 256, 0, stream>>>(Qb, tpos);
  rope_kernel<<<16384, 256, 0, stream>>>(Kb, tpos);

  flash_attn_mfma<<<dim3(32, 64), 256, 0, stream>>>(Qb, Kb, Vb, Ab);

  gemm_bt<<<gg, 256, 0, stream>>>(Ab, wo_bf, d_out, 1);
}

// Round 3
// 301.123 us; speedup vs baseline: 6.5449x; 1.6873x over previous
//
#include <hip/hip_runtime.h>
#include <stdint.h>

#define BATCH 4
#define SEQ 2048
#define DMODEL 1024
#define NHEADS 16
#define HDIM 64

typedef __attribute__((ext_vector_type(4))) short short4v;
typedef __attribute__((ext_vector_type(4))) float float4v;
typedef __attribute__((ext_vector_type(2))) unsigned int uint2v;
typedef __attribute__((ext_vector_type(4))) unsigned int uint4v;
typedef __attribute__((ext_vector_type(4))) unsigned short ushort4v;
typedef __attribute__((ext_vector_type(8))) __bf16 bf16x8;

union FragAB { short4v h[2]; unsigned int u[4]; bf16x8 v; };

__device__ __forceinline__ float bf2f(unsigned short u){
  union { unsigned int i; float f; } v; v.i = ((unsigned int)u) << 16; return v.f;
}
__device__ __forceinline__ unsigned short f2bf(float f){
  union { unsigned int i; float f; } v; v.f = f;
  unsigned int x = v.i;
  return (unsigned short)((x + 0x7FFFu + ((x >> 16) & 1u)) >> 16);
}

// ---------------- fp32 -> bf16 conversion (vector x4) ----------------
__global__ void cvt_f32_bf16(const float* __restrict__ in, unsigned short* __restrict__ out, int n4){
  int i = blockIdx.x * 256 + threadIdx.x;
  if (i < n4){
    float4v f = ((const float4v*)in)[i];
    ushort4v o;
    o[0]=f2bf(f[0]); o[1]=f2bf(f[1]); o[2]=f2bf(f[2]); o[3]=f2bf(f[3]);
    ((ushort4v*)out)[i] = o;
  }
}

// all 4 weight matrices in one launch; out = 4 contiguous 1M-elt bf16 blocks
__global__ void cvt_weights(const float* __restrict__ Wq, const float* __restrict__ Wk,
                            const float* __restrict__ Wv, const float* __restrict__ Wo,
                            unsigned short* __restrict__ out){
  int idx = blockIdx.x * 256 + threadIdx.x;   // 4 * 262144
  int mat = idx >> 18;
  int i   = idx & 262143;
  const float* src = (mat == 0) ? Wq : (mat == 1) ? Wk : (mat == 2) ? Wv : Wo;
  float4v f = ((const float4v*)src)[i];
  ushort4v o;
  o[0]=f2bf(f[0]); o[1]=f2bf(f[1]); o[2]=f2bf(f[2]); o[3]=f2bf(f[3]);
  ((ushort4v*)(out + (size_t)mat * 1048576))[i] = o;
}

// ---------------- bf16 GEMM 128x128 tile, BK=32, double-buffered ----------------
// C[m][n] = sum_k A[m][k]*W[n][k]
// mode 0: scatter bf16 to [B][H][S][HDIM] (Q,K)
// mode 1: fp32 row-major out[m*DMODEL+n]  (final)
// mode 2: scatter bf16 V^T to [B][H][HDIM][S]
__launch_bounds__(256)
__global__ void gemm128(const unsigned short* __restrict__ A,
                        const unsigned short* __restrict__ W,
                        void* __restrict__ out, const int mode)
{
  __shared__ unsigned short Al[2][128][40];
  __shared__ unsigned short Bl[2][128][40];

  const int tid  = threadIdx.x;
  const int wid  = tid >> 6, lane = tid & 63;
  const int lg   = lane >> 4, lr = lane & 15;
  const int wm   = wid >> 1, wn = wid & 1;
  const int m0   = blockIdx.y * 128;
  const int n0   = blockIdx.x * 128;
  const int lrow = tid >> 2;            // 0..63
  const int lcol = (tid & 3) * 8;       // 0,8,16,24

  float4v acc[4][4] = {};
  uint4v ar[2], br[2];

  #pragma unroll
  for (int p = 0; p < 2; ++p){
    ar[p] = *(const uint4v*)(A + (size_t)(m0 + p*64 + lrow) * DMODEL + lcol);
    br[p] = *(const uint4v*)(W + (size_t)(n0 + p*64 + lrow) * DMODEL + lcol);
  }
  #pragma unroll
  for (int p = 0; p < 2; ++p){
    *(uint4v*)&Al[0][p*64 + lrow][lcol] = ar[p];
    *(uint4v*)&Bl[0][p*64 + lrow][lcol] = br[p];
  }
  __syncthreads();

  int buf = 0;
  for (int k0 = 0; k0 < DMODEL; k0 += 32){
    if (k0 + 32 < DMODEL){
      #pragma unroll
      for (int p = 0; p < 2; ++p){
        ar[p] = *(const uint4v*)(A + (size_t)(m0 + p*64 + lrow) * DMODEL + k0 + 32 + lcol);
        br[p] = *(const uint4v*)(W + (size_t)(n0 + p*64 + lrow) * DMODEL + k0 + 32 + lcol);
      }
    }

    FragAB bfr[4];
    #pragma unroll
    for (int fn = 0; fn < 4; ++fn){
      const unsigned short* brow = &Bl[buf][wn*64 + fn*16 + lr][0];
      bfr[fn].h[0] = *(const short4v*)(brow + lg*4);
      bfr[fn].h[1] = *(const short4v*)(brow + 16 + lg*4);
    }
    #pragma unroll
    for (int fm = 0; fm < 4; ++fm){
      const unsigned short* arow = &Al[buf][wm*64 + fm*16 + lr][0];
      FragAB afr;
      afr.h[0] = *(const short4v*)(arow + lg*4);
      afr.h[1] = *(const short4v*)(arow + 16 + lg*4);
      #pragma unroll
      for (int fn = 0; fn < 4; ++fn)
        acc[fm][fn] = __builtin_amdgcn_mfma_f32_16x16x32_bf16(afr.v, bfr[fn].v, acc[fm][fn], 0, 0, 0);
    }

    if (k0 + 32 < DMODEL){
      #pragma unroll
      for (int p = 0; p < 2; ++p){
        *(uint4v*)&Al[buf^1][p*64 + lrow][lcol] = ar[p];
        *(uint4v*)&Bl[buf^1][p*64 + lrow][lcol] = br[p];
      }
    }
    __syncthreads();
    buf ^= 1;
  }

  #pragma unroll
  for (int fm = 0; fm < 4; ++fm)
    #pragma unroll
    for (int fn = 0; fn < 4; ++fn){
      const int gm = m0 + wm*64 + fm*16 + lg*4;   // +r
      const int gn = n0 + wn*64 + fn*16 + lr;
      if (mode == 1){
        float* op = (float*)out + (size_t)gm * DMODEL + gn;
        #pragma unroll
        for (int r = 0; r < 4; ++r) op[(size_t)r * DMODEL] = acc[fm][fn][r];
      } else if (mode == 0){
        const int b = gm >> 11, s = gm & (SEQ - 1);
        const int h = gn >> 6,  d = gn & (HDIM - 1);
        unsigned short* op = (unsigned short*)out + (((size_t)(b*NHEADS + h))*SEQ + s)*HDIM + d;
        #pragma unroll
        for (int r = 0; r < 4; ++r) op[(size_t)r * HDIM] = f2bf(acc[fm][fn][r]);
      } else {
        const int b = gm >> 11, s = gm & (SEQ - 1);
        const int h = gn >> 6,  d = gn & (HDIM - 1);
        unsigned short* op = (unsigned short*)out + (((size_t)(b*NHEADS + h))*HDIM + d)*SEQ + s;
        uint2v pk2;
        pk2[0] = (unsigned int)f2bf(acc[fm][fn][0]) | ((unsigned int)f2bf(acc[fm][fn][1]) << 16);
        pk2[1] = (unsigned int)f2bf(acc[fm][fn][2]) | ((unsigned int)f2bf(acc[fm][fn][3]) << 16);
        *(uint2v*)op = pk2;
      }
    }
}

// ---------------- RoPE in-place on [B][H][S][HDIM] bf16 (+ optional scale) ----------------
__global__ void rope_kernel(unsigned short* __restrict__ T, const int* __restrict__ pos, const float scale){
  int idx = blockIdx.x * 256 + threadIdx.x;
  if (idx >= BATCH*NHEADS*SEQ*32) return;
  int i  = idx & 31;
  int s  = (idx >> 5) & (SEQ - 1);
  int bh = idx >> 16;
  unsigned short* p = T + ((size_t)bh * SEQ + s) * HDIM + 2*i;
  float e = bf2f(p[0]), o = bf2f(p[1]);
  float inv = exp2f(-0.41524101186092030f * (float)i);
  float ang = (float)pos[s] * inv;
  float sn = sinf(ang), cs = cosf(ang);
  p[0] = f2bf((e*cs - o*sn) * scale);
  p[1] = f2bf((e*sn + o*cs) * scale);
}

// ---------------- MFMA causal flash attention v2 ----------------
// grid (16, 64): qtb = 15 - bx (long blocks first), 4 waves x 32 q-rows = 128 q/block.
// S^T = mfma(K, Q); P stays in registers as B-frag of O^T = mfma(V^T, P).
// V^T comes pre-transposed from global; double-buffered reg-staged pipeline.
__launch_bounds__(256, 2)
__global__ void flash_attn2(const unsigned short* __restrict__ Qg,
                            const unsigned short* __restrict__ Kg,
                            const unsigned short* __restrict__ VTg,
                            unsigned short* __restrict__ Og)
{
  __shared__ unsigned short Kl[2][64][72];
  __shared__ unsigned short Vt[2][64][72];

  const int tid  = threadIdx.x;
  const int w    = tid >> 6, lane = tid & 63;
  const int lg   = lane >> 4, lr = lane & 15;
  const int qtb  = 15 - blockIdx.x;
  const int bh   = blockIdx.y;
  const int q0   = qtb * 128;
  const size_t baseK = (size_t)bh * SEQ * HDIM;
  const size_t baseV = (size_t)bh * HDIM * SEQ;

  const int qmin  = q0 + w * 32;
  const int wlast = qmin >> 6;          // wave's diagonal tile
  const int nt    = 2 * qtb + 2;

  FragAB qf[2][2];
  int qglob[2];
  #pragma unroll
  for (int c = 0; c < 2; ++c){
    qglob[c] = qmin + 16*c + lr;
    const unsigned short* qrow = Qg + baseK + (size_t)qglob[c] * HDIM;
    qf[c][0].h[0] = *(const short4v*)(qrow + lg*4);
    qf[c][0].h[1] = *(const short4v*)(qrow + 16 + lg*4);
    qf[c][1].h[0] = *(const short4v*)(qrow + 32 + lg*4);
    qf[c][1].h[1] = *(const short4v*)(qrow + 48 + lg*4);
  }

  float4v o[2][4] = {};
  float mrun[2] = {-1e30f, -1e30f};
  float lrun[2] = {0.f, 0.f};

  const int sr  = tid >> 3;        // 0..31
  const int sc8 = (tid & 7) * 8;   // 0..56

  uint4v kreg[2], vreg[2];
  #pragma unroll
  for (int p = 0; p < 2; ++p){
    kreg[p] = *(const uint4v*)(Kg  + baseK + (size_t)(p*32 + sr) * HDIM + sc8);
    vreg[p] = *(const uint4v*)(VTg + baseV + (size_t)(p*32 + sr) * SEQ + sc8);
  }
  #pragma unroll
  for (int p = 0; p < 2; ++p){
    *(uint4v*)&Kl[0][p*32 + sr][sc8] = kreg[p];
    *(uint4v*)&Vt[0][p*32 + sr][sc8] = vreg[p];
  }
  __syncthreads();

  int buf = 0;
  for (int t = 0; t < nt; ++t){
    const int nxt = t + 1;
    if (nxt < nt){
      const int kv1 = nxt * 64;
      #pragma unroll
      for (int p = 0; p < 2; ++p){
        kreg[p] = *(const uint4v*)(Kg  + baseK + (size_t)(kv1 + p*32 + sr) * HDIM + sc8);
        vreg[p] = *(const uint4v*)(VTg + baseV + (size_t)(p*32 + sr) * SEQ + kv1 + sc8);
      }
    }

    if (t <= wlast){
      const int kv0 = t * 64;
      const bool diag = (t == wlast);
      float p4[2][4][4];

      #pragma unroll
      for (int kb = 0; kb < 4; ++kb){
        const unsigned short* krow = &Kl[buf][kb*16 + lr][0];
        FragAB kf0, kf1;
        kf0.h[0] = *(const short4v*)(krow + lg*4);
        kf0.h[1] = *(const short4v*)(krow + 16 + lg*4);
        kf1.h[0] = *(const short4v*)(krow + 32 + lg*4);
        kf1.h[1] = *(const short4v*)(krow + 48 + lg*4);
        #pragma unroll
        for (int c = 0; c < 2; ++c){
          float4v st = {};
          st = __builtin_amdgcn_mfma_f32_16x16x32_bf16(kf0.v, qf[c][0].v, st, 0, 0, 0);
          st = __builtin_amdgcn_mfma_f32_16x16x32_bf16(kf1.v, qf[c][1].v, st, 0, 0, 0);
          if (diag){
            #pragma unroll
            for (int r = 0; r < 4; ++r)
              p4[c][kb][r] = (kv0 + kb*16 + lg*4 + r <= qglob[c]) ? st[r] : -1e30f;
          } else {
            #pragma unroll
            for (int r = 0; r < 4; ++r) p4[c][kb][r] = st[r];
          }
        }
      }

      #pragma unroll
      for (int c = 0; c < 2; ++c){
        float rmax = p4[c][0][0];
        #pragma unroll
        for (int kb = 0; kb < 4; ++kb)
          #pragma unroll
          for (int r = 0; r < 4; ++r) rmax = fmaxf(rmax, p4[c][kb][r]);
        rmax = fmaxf(rmax, __shfl_xor(rmax, 16));
        rmax = fmaxf(rmax, __shfl_xor(rmax, 32));

        if (__any(rmax > mrun[c] + 8.f)){
          float mnew  = fmaxf(mrun[c], rmax);
          float alpha = __expf(mrun[c] - mnew);
          lrun[c] *= alpha;
          #pragma unroll
          for (int dm = 0; dm < 4; ++dm)
            #pragma unroll
            for (int r = 0; r < 4; ++r) o[c][dm][r] *= alpha;
          mrun[c] = mnew;
        }
        float rsum = 0.f;
        #pragma unroll
        for (int kb = 0; kb < 4; ++kb)
          #pragma unroll
          for (int r = 0; r < 4; ++r){
            float e = __expf(p4[c][kb][r] - mrun[c]);
            p4[c][kb][r] = e;
            rsum += e;
          }
        rsum += __shfl_xor(rsum, 16);
        rsum += __shfl_xor(rsum, 32);
        lrun[c] += rsum;
      }

      FragAB pf[2][2];
      #pragma unroll
      for (int c = 0; c < 2; ++c)
        #pragma unroll
        for (int kc = 0; kc < 2; ++kc){
          unsigned int u0, u1, u2, u3;
          asm("v_cvt_pk_bf16_f32 %0, %1, %2" : "=v"(u0) : "v"(p4[c][2*kc][0]),   "v"(p4[c][2*kc][1]));
          asm("v_cvt_pk_bf16_f32 %0, %1, %2" : "=v"(u1) : "v"(p4[c][2*kc][2]),   "v"(p4[c][2*kc][3]));
          asm("v_cvt_pk_bf16_f32 %0, %1, %2" : "=v"(u2) : "v"(p4[c][2*kc+1][0]), "v"(p4[c][2*kc+1][1]));
          asm("v_cvt_pk_bf16_f32 %0, %1, %2" : "=v"(u3) : "v"(p4[c][2*kc+1][2]), "v"(p4[c][2*kc+1][3]));
          pf[c][kc].u[0] = u0; pf[c][kc].u[1] = u1; pf[c][kc].u[2] = u2; pf[c][kc].u[3] = u3;
        }

      #pragma unroll
      for (int dm = 0; dm < 4; ++dm){
        const unsigned short* vrow = &Vt[buf][dm*16 + lr][0];
        #pragma unroll
        for (int kc = 0; kc < 2; ++kc){
          FragAB vf;
          vf.h[0] = *(const short4v*)(vrow + kc*32 + lg*4);
          vf.h[1] = *(const short4v*)(vrow + kc*32 + 16 + lg*4);
          #pragma unroll
          for (int c = 0; c < 2; ++c)
            o[c][dm] = __builtin_amdgcn_mfma_f32_16x16x32_bf16(vf.v, pf[c][kc].v, o[c][dm], 0, 0, 0);
        }
      }
    }

    if (nxt < nt){
      #pragma unroll
      for (int p = 0; p < 2; ++p){
        *(uint4v*)&Kl[buf^1][p*32 + sr][sc8] = kreg[p];
        *(uint4v*)&Vt[buf^1][p*32 + sr][sc8] = vreg[p];
      }
    }
    __syncthreads();
    buf ^= 1;
  }

  const int b = bh >> 4, h = bh & (NHEADS - 1);
  #pragma unroll
  for (int c = 0; c < 2; ++c){
    const float inv = 1.0f / lrun[c];
    unsigned short* orow = Og + ((size_t)(b*SEQ + qglob[c])) * DMODEL + h*HDIM;
    #pragma unroll
    for (int dm = 0; dm < 4; ++dm){
      uint2v pkd;
      pkd[0] = (unsigned int)f2bf(o[c][dm][0]*inv) | ((unsigned int)f2bf(o[c][dm][1]*inv) << 16);
      pkd[1] = (unsigned int)f2bf(o[c][dm][2]*inv) | ((unsigned int)f2bf(o[c][dm][3]*inv) << 16);
      *(uint2v*)(orow + dm*16 + lg*4) = pkd;
    }
  }
}

// ---------------- launch ----------------
extern "C" void kernel_launch(void* const* d_in, const int* in_sizes, int n_in,
                              void* d_out, int out_size, void* d_ws, size_t ws_size,
                              hipStream_t stream)
{
  const float* x  = (const float*)d_in[0];
  const float* Wq = (const float*)d_in[1];
  const float* Wk = (const float*)d_in[2];
  const float* Wv = (const float*)d_in[3];
  const float* Wo = (const float*)d_in[4];
  const int* tpos = (const int*)d_in[5];

  char* w = (char*)d_ws;
  const size_t XBF = 16777216;   // 8192*1024*2
  const size_t WBF = 2097152;    // 1024*1024*2
  unsigned short* x_bf  = (unsigned short*)(w);
  unsigned short* wq_bf = (unsigned short*)(w + XBF);
  unsigned short* wk_bf = (unsigned short*)(w + XBF + WBF);
  unsigned short* wv_bf = (unsigned short*)(w + XBF + 2*WBF);
  unsigned short* wo_bf = (unsigned short*)(w + XBF + 3*WBF);
  unsigned short* Qb  = (unsigned short*)(w + XBF + 4*WBF);
  unsigned short* Kb  = (unsigned short*)(w + XBF + 4*WBF + XBF);
  unsigned short* VTb = (unsigned short*)(w + XBF + 4*WBF + 2*XBF);
  unsigned short* Ab  = (unsigned short*)(w + XBF + 4*WBF + 3*XBF);

  cvt_f32_bf16<<<8192, 256, 0, stream>>>(x, x_bf, 2097152);
  cvt_weights<<<4096, 256, 0, stream>>>(Wq, Wk, Wv, Wo, wq_bf);

  dim3 gg(8, 64);
  gemm128<<<gg, 256, 0, stream>>>(x_bf, wq_bf, Qb, 0);
  gemm128<<<gg, 256, 0, stream>>>(x_bf, wk_bf, Kb, 0);
  gemm128<<<gg, 256, 0, stream>>>(x_bf, wv_bf, VTb, 2);

  rope_kernel<<<16384, 256, 0, stream>>>(Qb, tpos, 0.125f);
  rope_kernel<<<16384, 256, 0, stream>>>(Kb, tpos, 1.0f);

  flash_attn2<<<dim3(16, 64), 256, 0, stream>>>(Qb, Kb, VTb, Ab);

  gemm128<<<gg, 256, 0, stream>>>(Ab, wo_bf, d_out, 1);
}

// Round 4
// 243.931 us; speedup vs baseline: 8.0794x; 1.2345x over previous
//
#include <hip/hip_runtime.h>
#include <stdint.h>

#define BATCH 4
#define SEQ 2048
#define DMODEL 1024
#define NHEADS 16
#define HDIM 64

typedef __attribute__((ext_vector_type(4))) short short4v;
typedef __attribute__((ext_vector_type(4))) float float4v;
typedef __attribute__((ext_vector_type(4))) int int4v;
typedef __attribute__((ext_vector_type(2))) unsigned int uint2v;
typedef __attribute__((ext_vector_type(4))) unsigned int uint4v;
typedef __attribute__((ext_vector_type(4))) unsigned short ushort4v;
typedef __attribute__((ext_vector_type(8))) __bf16 bf16x8;

union FragAB { short4v h[2]; unsigned int u[4]; bf16x8 v; };

// 0.125 * log2(e)  (folded into Q rope so softmax runs in exp2 domain)
#define QSCALE 0.18033688011112042f
// theta^(-2i/64) = 2^(-i * 2*log2(10000)/64)
#define ROPE_L2 -0.41524101186092030f

__device__ __forceinline__ float bf2f(unsigned short u){
  union { unsigned int i; float f; } v; v.i = ((unsigned int)u) << 16; return v.f;
}
__device__ __forceinline__ unsigned short f2bf(float f){
  union { unsigned int i; float f; } v; v.f = f;
  unsigned int x = v.i;
  return (unsigned short)((x + 0x7FFFu + ((x >> 16) & 1u)) >> 16);
}

// ---------------- fp32 -> bf16 conversion (vector x4) ----------------
__global__ void cvt_f32_bf16(const float* __restrict__ in, unsigned short* __restrict__ out, int n4){
  int i = blockIdx.x * 256 + threadIdx.x;
  if (i < n4){
    float4v f = ((const float4v*)in)[i];
    ushort4v o;
    o[0]=f2bf(f[0]); o[1]=f2bf(f[1]); o[2]=f2bf(f[2]); o[3]=f2bf(f[3]);
    ((ushort4v*)out)[i] = o;
  }
}

// all 4 weight matrices in one launch; out = 4 contiguous 1M-elt bf16 blocks
__global__ void cvt_weights(const float* __restrict__ Wq, const float* __restrict__ Wk,
                            const float* __restrict__ Wv, const float* __restrict__ Wo,
                            unsigned short* __restrict__ out){
  int idx = blockIdx.x * 256 + threadIdx.x;   // 4 * 262144
  int mat = idx >> 18;
  int i   = idx & 262143;
  const float* src = (mat == 0) ? Wq : (mat == 1) ? Wk : (mat == 2) ? Wv : Wo;
  float4v f = ((const float4v*)src)[i];
  ushort4v o;
  o[0]=f2bf(f[0]); o[1]=f2bf(f[1]); o[2]=f2bf(f[2]); o[3]=f2bf(f[3]);
  ((ushort4v*)(out + (size_t)mat * 1048576))[i] = o;
}

// ---------------- bf16 GEMM 128x128 tile, BK=32, double-buffered ----------------
// C[m][n] = sum_k A[m][k]*W[n][k]
// MODE 0: fused QKV projection (N=3072) + RoPE on Q/K epilogue.
//         mat0 -> Qd [B][H][S][64] (scaled by QSCALE), mat1 -> Kd same,
//         mat2 -> Vd as V^T [B][H][64][S].
// MODE 1: fp32 row-major Fd[m*DMODEL+n] (final O-projection).
template<int MODE>
__launch_bounds__(256)
__global__ void gemm128t(const unsigned short* __restrict__ A,
                         const unsigned short* __restrict__ W,
                         unsigned short* __restrict__ Qd,
                         unsigned short* __restrict__ Kd,
                         unsigned short* __restrict__ Vd,
                         float* __restrict__ Fd,
                         const int* __restrict__ pos)
{
  __shared__ unsigned short Al[2][128][40];
  __shared__ unsigned short Bl[2][128][40];

  const int tid  = threadIdx.x;
  const int wid  = tid >> 6, lane = tid & 63;
  const int lg   = lane >> 4, lr = lane & 15;
  const int wm   = wid >> 1, wn = wid & 1;
  const int m0   = blockIdx.y * 128;
  const int n0   = blockIdx.x * 128;
  const int lrow = tid >> 2;            // 0..63
  const int lcol = (tid & 3) * 8;       // 0,8,16,24

  float4v acc[4][4] = {};
  uint4v ar[2], br[2];

  #pragma unroll
  for (int p = 0; p < 2; ++p){
    ar[p] = *(const uint4v*)(A + (size_t)(m0 + p*64 + lrow) * DMODEL + lcol);
    br[p] = *(const uint4v*)(W + (size_t)(n0 + p*64 + lrow) * DMODEL + lcol);
  }
  #pragma unroll
  for (int p = 0; p < 2; ++p){
    *(uint4v*)&Al[0][p*64 + lrow][lcol] = ar[p];
    *(uint4v*)&Bl[0][p*64 + lrow][lcol] = br[p];
  }
  __syncthreads();

  int buf = 0;
  for (int k0 = 0; k0 < DMODEL; k0 += 32){
    if (k0 + 32 < DMODEL){
      #pragma unroll
      for (int p = 0; p < 2; ++p){
        ar[p] = *(const uint4v*)(A + (size_t)(m0 + p*64 + lrow) * DMODEL + k0 + 32 + lcol);
        br[p] = *(const uint4v*)(W + (size_t)(n0 + p*64 + lrow) * DMODEL + k0 + 32 + lcol);
      }
    }

    FragAB bfr[4];
    #pragma unroll
    for (int fn = 0; fn < 4; ++fn){
      const unsigned short* brow = &Bl[buf][wn*64 + fn*16 + lr][0];
      bfr[fn].h[0] = *(const short4v*)(brow + lg*4);
      bfr[fn].h[1] = *(const short4v*)(brow + 16 + lg*4);
    }
    #pragma unroll
    for (int fm = 0; fm < 4; ++fm){
      const unsigned short* arow = &Al[buf][wm*64 + fm*16 + lr][0];
      FragAB afr;
      afr.h[0] = *(const short4v*)(arow + lg*4);
      afr.h[1] = *(const short4v*)(arow + 16 + lg*4);
      #pragma unroll
      for (int fn = 0; fn < 4; ++fn)
        acc[fm][fn] = __builtin_amdgcn_mfma_f32_16x16x32_bf16(afr.v, bfr[fn].v, acc[fm][fn], 0, 0, 0);
    }

    if (k0 + 32 < DMODEL){
      #pragma unroll
      for (int p = 0; p < 2; ++p){
        *(uint4v*)&Al[buf^1][p*64 + lrow][lcol] = ar[p];
        *(uint4v*)&Bl[buf^1][p*64 + lrow][lcol] = br[p];
      }
    }
    __syncthreads();
    buf ^= 1;
  }

  #pragma unroll
  for (int fm = 0; fm < 4; ++fm)
    #pragma unroll
    for (int fn = 0; fn < 4; ++fn){
      const int gm = m0 + wm*64 + fm*16 + lg*4;   // +r
      const int gn = n0 + wn*64 + fn*16 + lr;
      if (MODE == 1){
        float* op = Fd + (size_t)gm * DMODEL + gn;
        #pragma unroll
        for (int r = 0; r < 4; ++r) op[(size_t)r * DMODEL] = acc[fm][fn][r];
      } else {
        const int mat = gn >> 10;
        const int b = gm >> 11, s = gm & (SEQ - 1);
        const int h = (gn >> 6) & (NHEADS - 1), d = gn & (HDIM - 1);
        if (mat == 2){
          unsigned short* op = Vd + (((size_t)(b*NHEADS + h))*HDIM + d)*SEQ + s;
          uint2v pk2;
          pk2[0] = (unsigned int)f2bf(acc[fm][fn][0]) | ((unsigned int)f2bf(acc[fm][fn][1]) << 16);
          pk2[1] = (unsigned int)f2bf(acc[fm][fn][2]) | ((unsigned int)f2bf(acc[fm][fn][3]) << 16);
          *(uint2v*)op = pk2;
        } else {
          // fused RoPE: pair (d even, d odd) sits in lanes lr^1
          int4v p4v = *(const int4v*)(pos + s);
          const float invf = exp2f(ROPE_L2 * (float)(d >> 1));
          const float sgn  = (d & 1) ? 1.f : -1.f;
          const float scl  = (mat == 0) ? QSCALE : 1.0f;
          unsigned short* op = (mat == 0 ? Qd : Kd) + (((size_t)(b*NHEADS + h))*SEQ + s)*HDIM + d;
          #pragma unroll
          for (int r = 0; r < 4; ++r){
            float v  = acc[fm][fn][r];
            float pv = __shfl_xor(v, 1);
            float ang = (float)p4v[r] * invf;
            float sn, cs;
            __sincosf(ang, &sn, &cs);
            op[(size_t)r * HDIM] = f2bf((v*cs + pv*sn*sgn) * scl);
          }
        }
      }
    }
}

// ---------------- MFMA causal flash attention v3 ----------------
// grid (8, 64): block bx handles q-tile pair {15-bx, bx} (uniform 34 K-tiles).
// 4 waves x 32 q-rows = 128 q/phase. S^T = mfma(K, Q); P stays in registers as
// B-frag of O^T = mfma(V^T, P). V^T pre-transposed in global. Softmax in exp2
// domain (Q pre-scaled by 0.125*log2e). Double-buffered reg-staged pipeline.
__launch_bounds__(256, 4)
__global__ void flash_attn3(const unsigned short* __restrict__ Qg,
                            const unsigned short* __restrict__ Kg,
                            const unsigned short* __restrict__ VTg,
                            unsigned short* __restrict__ Og)
{
  __shared__ unsigned short Kl[2][64][72];
  __shared__ unsigned short Vt[2][64][72];

  const int tid  = threadIdx.x;
  const int w    = tid >> 6, lane = tid & 63;
  const int lg   = lane >> 4, lr = lane & 15;
  const int bx   = blockIdx.x;
  const int bh   = blockIdx.y;
  const size_t baseK = (size_t)bh * SEQ * HDIM;
  const size_t baseV = (size_t)bh * HDIM * SEQ;
  const int b = bh >> 4, h = bh & (NHEADS - 1);

  const int sr  = tid >> 3;        // 0..31
  const int sc8 = (tid & 7) * 8;   // 0..56

  #pragma unroll 1
  for (int ph = 0; ph < 2; ++ph){
    const int qtb  = ph ? bx : 15 - bx;
    const int q0   = qtb * 128;
    const int qmin = q0 + w * 32;
    const int wlast = qmin >> 6;
    const int nt    = 2 * qtb + 2;

    FragAB qf[2][2];
    int qglob[2];
    #pragma unroll
    for (int c = 0; c < 2; ++c){
      qglob[c] = qmin + 16*c + lr;
      const unsigned short* qrow = Qg + baseK + (size_t)qglob[c] * HDIM;
      qf[c][0].h[0] = *(const short4v*)(qrow + lg*4);
      qf[c][0].h[1] = *(const short4v*)(qrow + 16 + lg*4);
      qf[c][1].h[0] = *(const short4v*)(qrow + 32 + lg*4);
      qf[c][1].h[1] = *(const short4v*)(qrow + 48 + lg*4);
    }

    float4v o[2][4] = {};
    float mrun[2] = {-1e30f, -1e30f};
    float lrun[2] = {0.f, 0.f};

    uint4v kreg[2], vreg[2];
    #pragma unroll
    for (int p = 0; p < 2; ++p){
      kreg[p] = *(const uint4v*)(Kg  + baseK + (size_t)(p*32 + sr) * HDIM + sc8);
      vreg[p] = *(const uint4v*)(VTg + baseV + (size_t)(p*32 + sr) * SEQ + sc8);
    }
    #pragma unroll
    for (int p = 0; p < 2; ++p){
      *(uint4v*)&Kl[0][p*32 + sr][sc8] = kreg[p];
      *(uint4v*)&Vt[0][p*32 + sr][sc8] = vreg[p];
    }
    __syncthreads();

    int buf = 0;
    for (int t = 0; t < nt; ++t){
      const int nxt = t + 1;
      if (nxt < nt){
        const int kv1 = nxt * 64;
        #pragma unroll
        for (int p = 0; p < 2; ++p){
          kreg[p] = *(const uint4v*)(Kg  + baseK + (size_t)(kv1 + p*32 + sr) * HDIM + sc8);
          vreg[p] = *(const uint4v*)(VTg + baseV + (size_t)(p*32 + sr) * SEQ + kv1 + sc8);
        }
      }

      if (t <= wlast){
        const int kv0 = t * 64;
        const bool diag = (t == wlast);
        float p4[2][4][4];

        __builtin_amdgcn_s_setprio(1);
        #pragma unroll
        for (int kb = 0; kb < 4; ++kb){
          const unsigned short* krow = &Kl[buf][kb*16 + lr][0];
          FragAB kf0, kf1;
          kf0.h[0] = *(const short4v*)(krow + lg*4);
          kf0.h[1] = *(const short4v*)(krow + 16 + lg*4);
          kf1.h[0] = *(const short4v*)(krow + 32 + lg*4);
          kf1.h[1] = *(const short4v*)(krow + 48 + lg*4);
          #pragma unroll
          for (int c = 0; c < 2; ++c){
            float4v st = {};
            st = __builtin_amdgcn_mfma_f32_16x16x32_bf16(kf0.v, qf[c][0].v, st, 0, 0, 0);
            st = __builtin_amdgcn_mfma_f32_16x16x32_bf16(kf1.v, qf[c][1].v, st, 0, 0, 0);
            if (diag){
              #pragma unroll
              for (int r = 0; r < 4; ++r)
                p4[c][kb][r] = (kv0 + kb*16 + lg*4 + r <= qglob[c]) ? st[r] : -1e30f;
            } else {
              #pragma unroll
              for (int r = 0; r < 4; ++r) p4[c][kb][r] = st[r];
            }
          }
        }
        __builtin_amdgcn_s_setprio(0);

        #pragma unroll
        for (int c = 0; c < 2; ++c){
          float rmax = p4[c][0][0];
          #pragma unroll
          for (int kb = 0; kb < 4; ++kb)
            #pragma unroll
            for (int r = 0; r < 4; ++r) rmax = fmaxf(rmax, p4[c][kb][r]);
          rmax = fmaxf(rmax, __shfl_xor(rmax, 16));
          rmax = fmaxf(rmax, __shfl_xor(rmax, 32));

          if (__any(rmax > mrun[c] + 11.5f)){   // defer-max, exp2 domain
            float mnew  = fmaxf(mrun[c], rmax);
            float alpha = exp2f(mrun[c] - mnew);
            lrun[c] *= alpha;
            #pragma unroll
            for (int dm = 0; dm < 4; ++dm)
              #pragma unroll
              for (int r = 0; r < 4; ++r) o[c][dm][r] *= alpha;
            mrun[c] = mnew;
          }
          float rsum = 0.f;
          #pragma unroll
          for (int kb = 0; kb < 4; ++kb)
            #pragma unroll
            for (int r = 0; r < 4; ++r){
              float e = exp2f(p4[c][kb][r] - mrun[c]);
              p4[c][kb][r] = e;
              rsum += e;
            }
          rsum += __shfl_xor(rsum, 16);
          rsum += __shfl_xor(rsum, 32);
          lrun[c] += rsum;
        }

        FragAB pf[2][2];
        #pragma unroll
        for (int c = 0; c < 2; ++c)
          #pragma unroll
          for (int kc = 0; kc < 2; ++kc){
            unsigned int u0, u1, u2, u3;
            asm("v_cvt_pk_bf16_f32 %0, %1, %2" : "=v"(u0) : "v"(p4[c][2*kc][0]),   "v"(p4[c][2*kc][1]));
            asm("v_cvt_pk_bf16_f32 %0, %1, %2" : "=v"(u1) : "v"(p4[c][2*kc][2]),   "v"(p4[c][2*kc][3]));
            asm("v_cvt_pk_bf16_f32 %0, %1, %2" : "=v"(u2) : "v"(p4[c][2*kc+1][0]), "v"(p4[c][2*kc+1][1]));
            asm("v_cvt_pk_bf16_f32 %0, %1, %2" : "=v"(u3) : "v"(p4[c][2*kc+1][2]), "v"(p4[c][2*kc+1][3]));
            pf[c][kc].u[0] = u0; pf[c][kc].u[1] = u1; pf[c][kc].u[2] = u2; pf[c][kc].u[3] = u3;
          }

        __builtin_amdgcn_s_setprio(1);
        #pragma unroll
        for (int dm = 0; dm < 4; ++dm){
          const unsigned short* vrow = &Vt[buf][dm*16 + lr][0];
          #pragma unroll
          for (int kc = 0; kc < 2; ++kc){
            FragAB vf;
            vf.h[0] = *(const short4v*)(vrow + kc*32 + lg*4);
            vf.h[1] = *(const short4v*)(vrow + kc*32 + 16 + lg*4);
            #pragma unroll
            for (int c = 0; c < 2; ++c)
              o[c][dm] = __builtin_amdgcn_mfma_f32_16x16x32_bf16(vf.v, pf[c][kc].v, o[c][dm], 0, 0, 0);
          }
        }
        __builtin_amdgcn_s_setprio(0);
      }

      if (nxt < nt){
        #pragma unroll
        for (int p = 0; p < 2; ++p){
          *(uint4v*)&Kl[buf^1][p*32 + sr][sc8] = kreg[p];
          *(uint4v*)&Vt[buf^1][p*32 + sr][sc8] = vreg[p];
        }
      }
      __syncthreads();
      buf ^= 1;
    }

    #pragma unroll
    for (int c = 0; c < 2; ++c){
      const float inv = 1.0f / lrun[c];
      unsigned short* orow = Og + ((size_t)(b*SEQ + qglob[c])) * DMODEL + h*HDIM;
      #pragma unroll
      for (int dm = 0; dm < 4; ++dm){
        uint2v pkd;
        pkd[0] = (unsigned int)f2bf(o[c][dm][0]*inv) | ((unsigned int)f2bf(o[c][dm][1]*inv) << 16);
        pkd[1] = (unsigned int)f2bf(o[c][dm][2]*inv) | ((unsigned int)f2bf(o[c][dm][3]*inv) << 16);
        *(uint2v*)(orow + dm*16 + lg*4) = pkd;
      }
    }
  }
}

// ---------------- launch ----------------
extern "C" void kernel_launch(void* const* d_in, const int* in_sizes, int n_in,
                              void* d_out, int out_size, void* d_ws, size_t ws_size,
                              hipStream_t stream)
{
  const float* x  = (const float*)d_in[0];
  const float* Wq = (const float*)d_in[1];
  const float* Wk = (const float*)d_in[2];
  const float* Wv = (const float*)d_in[3];
  const float* Wo = (const float*)d_in[4];
  const int* tpos = (const int*)d_in[5];

  char* w = (char*)d_ws;
  const size_t XBF = 16777216;   // 8192*1024*2
  const size_t WBF = 2097152;    // 1024*1024*2
  unsigned short* x_bf  = (unsigned short*)(w);
  unsigned short* wq_bf = (unsigned short*)(w + XBF);
  unsigned short* wo_bf = (unsigned short*)(w + XBF + 3*WBF);
  unsigned short* Qb  = (unsigned short*)(w + XBF + 4*WBF);
  unsigned short* Kb  = (unsigned short*)(w + XBF + 4*WBF + XBF);
  unsigned short* VTb = (unsigned short*)(w + XBF + 4*WBF + 2*XBF);
  unsigned short* Ab  = (unsigned short*)(w + XBF + 4*WBF + 3*XBF);

  cvt_f32_bf16<<<8192, 256, 0, stream>>>(x, x_bf, 2097152);
  cvt_weights<<<4096, 256, 0, stream>>>(Wq, Wk, Wv, Wo, wq_bf);

  // fused QKV projection + RoPE (N = 3072)
  gemm128t<0><<<dim3(24, 64), 256, 0, stream>>>(x_bf, wq_bf, Qb, Kb, VTb, nullptr, tpos);

  flash_attn3<<<dim3(8, 64), 256, 0, stream>>>(Qb, Kb, VTb, Ab);

  // final O-projection -> fp32 d_out
  gemm128t<1><<<dim3(8, 64), 256, 0, stream>>>(Ab, wo_bf, nullptr, nullptr, nullptr, (float*)d_out, tpos);
}

// Round 5
// 198.245 us; speedup vs baseline: 9.9413x; 1.2305x over previous
//
#include <hip/hip_runtime.h>
#include <stdint.h>

#define BATCH 4
#define SEQ 2048
#define DMODEL 1024
#define NHEADS 16
#define HDIM 64

typedef __attribute__((ext_vector_type(4))) short short4v;
typedef __attribute__((ext_vector_type(4))) float float4v;
typedef __attribute__((ext_vector_type(4))) int int4v;
typedef __attribute__((ext_vector_type(2))) unsigned int uint2v;
typedef __attribute__((ext_vector_type(4))) unsigned int uint4v;
typedef __attribute__((ext_vector_type(4))) unsigned short ushort4v;
typedef __attribute__((ext_vector_type(8))) __bf16 bf16x8;

union FragAB { short4v h[2]; unsigned int u[4]; bf16x8 v; };

// 0.125 * log2(e)  (folded into Q rope so softmax runs in exp2 domain)
#define QSCALE 0.18033688011112042f
// theta^(-2i/64) = 2^(-i * 2*log2(10000)/64)
#define ROPE_L2 -0.41524101186092030f

__device__ __forceinline__ float bf2f(unsigned short u){
  union { unsigned int i; float f; } v; v.i = ((unsigned int)u) << 16; return v.f;
}
__device__ __forceinline__ unsigned short f2bf(float f){
  union { unsigned int i; float f; } v; v.f = f;
  unsigned int x = v.i;
  return (unsigned short)((x + 0x7FFFu + ((x >> 16) & 1u)) >> 16);
}

// async global -> LDS, 16B per lane. LDS dest: wave-uniform base + lane*16.
__device__ __forceinline__ void gload16(const unsigned short* g, unsigned short* l){
  __builtin_amdgcn_global_load_lds(
      (const __attribute__((address_space(1))) void*)g,
      (__attribute__((address_space(3))) void*)l, 16, 0, 0);
}

// ---------------- fp32 -> bf16 conversion (vector x4) ----------------
__global__ void cvt_f32_bf16(const float* __restrict__ in, unsigned short* __restrict__ out, int n4){
  int i = blockIdx.x * 256 + threadIdx.x;
  if (i < n4){
    float4v f = ((const float4v*)in)[i];
    ushort4v o;
    o[0]=f2bf(f[0]); o[1]=f2bf(f[1]); o[2]=f2bf(f[2]); o[3]=f2bf(f[3]);
    ((ushort4v*)out)[i] = o;
  }
}

// all 4 weight matrices in one launch; out = 4 contiguous 1M-elt bf16 blocks
__global__ void cvt_weights(const float* __restrict__ Wq, const float* __restrict__ Wk,
                            const float* __restrict__ Wv, const float* __restrict__ Wo,
                            unsigned short* __restrict__ out){
  int idx = blockIdx.x * 256 + threadIdx.x;   // 4 * 262144
  int mat = idx >> 18;
  int i   = idx & 262143;
  const float* src = (mat == 0) ? Wq : (mat == 1) ? Wk : (mat == 2) ? Wv : Wo;
  float4v f = ((const float4v*)src)[i];
  ushort4v o;
  o[0]=f2bf(f[0]); o[1]=f2bf(f[1]); o[2]=f2bf(f[2]); o[3]=f2bf(f[3]);
  ((ushort4v*)(out + (size_t)mat * 1048576))[i] = o;
}

// ---------------- bf16 GEMM 128x128 tile, BK=32, global_load_lds staging ----------------
// C[m][n] = sum_k A[m][k]*W[n][k]
// MODE 0: fused QKV projection (N=3072) + RoPE on Q/K epilogue.
// MODE 1: fp32 row-major Fd[m*DMODEL+n] (final O-projection).
// LDS linear (no pad): required by global_load_lds wave-uniform-dest semantics.
// Fragments load as contiguous b128 (k = lg*8+j); same sigma on A and B -> sum invariant.
template<int MODE>
__launch_bounds__(256, 3)
__global__ void gemm_gl(const unsigned short* __restrict__ A,
                        const unsigned short* __restrict__ W,
                        unsigned short* __restrict__ Qd,
                        unsigned short* __restrict__ Kd,
                        unsigned short* __restrict__ Vd,
                        float* __restrict__ Fd,
                        const int* __restrict__ pos)
{
  __shared__ __align__(16) unsigned short Al[2][128][32];
  __shared__ __align__(16) unsigned short Bl[2][128][32];

  const int tid  = threadIdx.x;
  const int wid  = tid >> 6, lane = tid & 63;
  const int lg   = lane >> 4, lr = lane & 15;
  const int wm   = wid >> 1, wn = wid & 1;
  const int m0   = blockIdx.y * 128;
  const int n0   = blockIdx.x * 128;

  // staging: instruction covers 16 rows (64 lanes x 16B); lane l -> row +l/4, col (l&3)*8
  const int gsr = wid*32 + (lane >> 2);   // + i*16
  const int gsc = (lane & 3) * 8;

  const unsigned short* Ab = A + (size_t)(m0 + gsr) * DMODEL + gsc;
  const unsigned short* Wb = W + (size_t)(n0 + gsr) * DMODEL + gsc;

  float4v acc[4][4] = {};

  // prologue stage
  #pragma unroll
  for (int i = 0; i < 2; ++i){
    gload16(Ab + (size_t)i*16*DMODEL, &Al[0][wid*32 + i*16][0]);
    gload16(Wb + (size_t)i*16*DMODEL, &Bl[0][wid*32 + i*16][0]);
  }
  __syncthreads();

  int buf = 0;
  for (int k0 = 0; k0 < DMODEL; k0 += 32){
    if (k0 + 32 < DMODEL){
      #pragma unroll
      for (int i = 0; i < 2; ++i){
        gload16(Ab + (size_t)i*16*DMODEL + k0 + 32, &Al[buf^1][wid*32 + i*16][0]);
        gload16(Wb + (size_t)i*16*DMODEL + k0 + 32, &Bl[buf^1][wid*32 + i*16][0]);
      }
    }

    FragAB afr[4], bfr[4];
    #pragma unroll
    for (int f = 0; f < 4; ++f){
      afr[f].v = *(const bf16x8*)&Al[buf][wm*64 + f*16 + lr][lg*8];
      bfr[f].v = *(const bf16x8*)&Bl[buf][wn*64 + f*16 + lr][lg*8];
    }
    #pragma unroll
    for (int fm = 0; fm < 4; ++fm)
      #pragma unroll
      for (int fn = 0; fn < 4; ++fn)
        acc[fm][fn] = __builtin_amdgcn_mfma_f32_16x16x32_bf16(afr[fm].v, bfr[fn].v, acc[fm][fn], 0, 0, 0);

    __syncthreads();   // drains gload_lds (vmcnt0) + protects buf reuse
    buf ^= 1;
  }

  #pragma unroll
  for (int fm = 0; fm < 4; ++fm)
    #pragma unroll
    for (int fn = 0; fn < 4; ++fn){
      const int gm = m0 + wm*64 + fm*16 + lg*4;   // +r
      const int gn = n0 + wn*64 + fn*16 + lr;
      if (MODE == 1){
        float* op = Fd + (size_t)gm * DMODEL + gn;
        #pragma unroll
        for (int r = 0; r < 4; ++r) op[(size_t)r * DMODEL] = acc[fm][fn][r];
      } else {
        const int mat = gn >> 10;
        const int b = gm >> 11, s = gm & (SEQ - 1);
        const int h = (gn >> 6) & (NHEADS - 1), d = gn & (HDIM - 1);
        if (mat == 2){
          unsigned short* op = Vd + (((size_t)(b*NHEADS + h))*HDIM + d)*SEQ + s;
          uint2v pk2;
          pk2[0] = (unsigned int)f2bf(acc[fm][fn][0]) | ((unsigned int)f2bf(acc[fm][fn][1]) << 16);
          pk2[1] = (unsigned int)f2bf(acc[fm][fn][2]) | ((unsigned int)f2bf(acc[fm][fn][3]) << 16);
          *(uint2v*)op = pk2;
        } else {
          // fused RoPE: pair (d even, d odd) sits in lanes lr^1
          int4v p4v = *(const int4v*)(pos + s);
          const float invf = exp2f(ROPE_L2 * (float)(d >> 1));
          const float sgn  = (d & 1) ? 1.f : -1.f;
          const float scl  = (mat == 0) ? QSCALE : 1.0f;
          unsigned short* op = (mat == 0 ? Qd : Kd) + (((size_t)(b*NHEADS + h))*SEQ + s)*HDIM + d;
          #pragma unroll
          for (int r = 0; r < 4; ++r){
            float v  = acc[fm][fn][r];
            float pv = __shfl_xor(v, 1);
            float ang = (float)p4v[r] * invf;
            float sn, cs;
            __sincosf(ang, &sn, &cs);
            op[(size_t)r * HDIM] = f2bf((v*cs + pv*sn*sgn) * scl);
          }
        }
      }
    }
}

// ---------------- MFMA causal flash attention v4: 8 waves, 16 q-rows/wave ----------------
// grid (8, 64): block bx handles q-tile pair {15-bx, bx} (uniform 34 K-tiles).
// 512 threads = 8 waves; 2 blocks/CU -> 4 waves/SIMD for MFMA/VALU/trans overlap.
// S^T = mfma(K, Q); P stays in registers as B-frag of O^T = mfma(V^T, P).
__launch_bounds__(512, 4)
__global__ void flash_attn4(const unsigned short* __restrict__ Qg,
                            const unsigned short* __restrict__ Kg,
                            const unsigned short* __restrict__ VTg,
                            unsigned short* __restrict__ Og)
{
  __shared__ __align__(16) unsigned short Kl[2][64][72];
  __shared__ __align__(16) unsigned short Vt[2][64][72];

  const int tid  = threadIdx.x;
  const int w    = tid >> 6, lane = tid & 63;
  const int lg   = lane >> 4, lr = lane & 15;
  const int bx   = blockIdx.x;
  const int bh   = blockIdx.y;
  const size_t baseK = (size_t)bh * SEQ * HDIM;
  const size_t baseV = (size_t)bh * HDIM * SEQ;
  const int b = bh >> 4, h = bh & (NHEADS - 1);

  const int sr  = tid >> 3;        // 0..63
  const int sc8 = (tid & 7) * 8;   // 0..56

  #pragma unroll 1
  for (int ph = 0; ph < 2; ++ph){
    const int qtb   = ph ? bx : 15 - bx;
    const int q0    = qtb * 128;
    const int qmin  = q0 + w * 16;
    const int wlast = qmin >> 6;
    const int nt    = 2 * qtb + 2;
    const int qglob = qmin + lr;

    // Q frags (B operand), contiguous sigma: chunk c holds d = c*32 + lg*8 + j
    FragAB qf[2];
    {
      const unsigned short* qrow = Qg + baseK + (size_t)qglob * HDIM;
      qf[0].v = *(const bf16x8*)(qrow + lg*8);
      qf[1].v = *(const bf16x8*)(qrow + 32 + lg*8);
    }

    float4v o[4] = {};
    float mrun = -1e30f, lrun = 0.f;

    uint4v kreg, vreg;
    kreg = *(const uint4v*)(Kg  + baseK + (size_t)sr * HDIM + sc8);
    vreg = *(const uint4v*)(VTg + baseV + (size_t)sr * SEQ + sc8);
    *(uint4v*)&Kl[0][sr][sc8] = kreg;
    *(uint4v*)&Vt[0][sr][sc8] = vreg;
    __syncthreads();

    int buf = 0;
    for (int t = 0; t < nt; ++t){
      const int nxt = t + 1;
      if (nxt < nt){
        const int kv1 = nxt * 64;
        kreg = *(const uint4v*)(Kg  + baseK + (size_t)(kv1 + sr) * HDIM + sc8);
        vreg = *(const uint4v*)(VTg + baseV + (size_t)sr * SEQ + kv1 + sc8);
      }

      if (t <= wlast){
        const int kv0 = t * 64;
        const bool diag = (t == wlast);
        float p4[4][4];

        __builtin_amdgcn_s_setprio(1);
        #pragma unroll
        for (int kb = 0; kb < 4; ++kb){
          const unsigned short* krow = &Kl[buf][kb*16 + lr][0];
          FragAB kf0, kf1;
          kf0.v = *(const bf16x8*)(krow + lg*8);
          kf1.v = *(const bf16x8*)(krow + 32 + lg*8);
          float4v st = {};
          st = __builtin_amdgcn_mfma_f32_16x16x32_bf16(kf0.v, qf[0].v, st, 0, 0, 0);
          st = __builtin_amdgcn_mfma_f32_16x16x32_bf16(kf1.v, qf[1].v, st, 0, 0, 0);
          if (diag){
            #pragma unroll
            for (int r = 0; r < 4; ++r)
              p4[kb][r] = (kv0 + kb*16 + lg*4 + r <= qglob) ? st[r] : -1e30f;
          } else {
            #pragma unroll
            for (int r = 0; r < 4; ++r) p4[kb][r] = st[r];
          }
        }
        __builtin_amdgcn_s_setprio(0);

        float rmax = p4[0][0];
        #pragma unroll
        for (int kb = 0; kb < 4; ++kb)
          #pragma unroll
          for (int r = 0; r < 4; ++r) rmax = fmaxf(rmax, p4[kb][r]);
        rmax = fmaxf(rmax, __shfl_xor(rmax, 16));
        rmax = fmaxf(rmax, __shfl_xor(rmax, 32));

        if (__any(rmax > mrun + 11.5f)){   // defer-max, exp2 domain
          float mnew  = fmaxf(mrun, rmax);
          float alpha = exp2f(mrun - mnew);
          lrun *= alpha;
          #pragma unroll
          for (int dm = 0; dm < 4; ++dm)
            #pragma unroll
            for (int r = 0; r < 4; ++r) o[dm][r] *= alpha;
          mrun = mnew;
        }
        float rsum = 0.f;
        #pragma unroll
        for (int kb = 0; kb < 4; ++kb)
          #pragma unroll
          for (int r = 0; r < 4; ++r){
            float e = exp2f(p4[kb][r] - mrun);
            p4[kb][r] = e;
            rsum += e;
          }
        rsum += __shfl_xor(rsum, 16);
        rsum += __shfl_xor(rsum, 32);
        lrun += rsum;

        // P -> bf16 frags: pf[kc].h[0] = p4[2kc][j] (k=lg*4+j), h[1] = p4[2kc+1][j] (k=16+lg*4+j)
        FragAB pf[2];
        #pragma unroll
        for (int kc = 0; kc < 2; ++kc){
          unsigned int u0, u1, u2, u3;
          asm("v_cvt_pk_bf16_f32 %0, %1, %2" : "=v"(u0) : "v"(p4[2*kc][0]),   "v"(p4[2*kc][1]));
          asm("v_cvt_pk_bf16_f32 %0, %1, %2" : "=v"(u1) : "v"(p4[2*kc][2]),   "v"(p4[2*kc][3]));
          asm("v_cvt_pk_bf16_f32 %0, %1, %2" : "=v"(u2) : "v"(p4[2*kc+1][0]), "v"(p4[2*kc+1][1]));
          asm("v_cvt_pk_bf16_f32 %0, %1, %2" : "=v"(u3) : "v"(p4[2*kc+1][2]), "v"(p4[2*kc+1][3]));
          pf[kc].u[0] = u0; pf[kc].u[1] = u1; pf[kc].u[2] = u2; pf[kc].u[3] = u3;
        }

        __builtin_amdgcn_s_setprio(1);
        #pragma unroll
        for (int dm = 0; dm < 4; ++dm){
          const unsigned short* vrow = &Vt[buf][dm*16 + lr][0];
          #pragma unroll
          for (int kc = 0; kc < 2; ++kc){
            FragAB vf;   // split sigma matches pf construction
            vf.h[0] = *(const short4v*)(vrow + kc*32 + lg*4);
            vf.h[1] = *(const short4v*)(vrow + kc*32 + 16 + lg*4);
            o[dm] = __builtin_amdgcn_mfma_f32_16x16x32_bf16(vf.v, pf[kc].v, o[dm], 0, 0, 0);
          }
        }
        __builtin_amdgcn_s_setprio(0);
      }

      if (nxt < nt){
        *(uint4v*)&Kl[buf^1][sr][sc8] = kreg;
        *(uint4v*)&Vt[buf^1][sr][sc8] = vreg;
      }
      __syncthreads();
      buf ^= 1;
    }

    const float inv = 1.0f / lrun;
    unsigned short* orow = Og + ((size_t)(b*SEQ + qglob)) * DMODEL + h*HDIM;
    #pragma unroll
    for (int dm = 0; dm < 4; ++dm){
      uint2v pkd;
      pkd[0] = (unsigned int)f2bf(o[dm][0]*inv) | ((unsigned int)f2bf(o[dm][1]*inv) << 16);
      pkd[1] = (unsigned int)f2bf(o[dm][2]*inv) | ((unsigned int)f2bf(o[dm][3]*inv) << 16);
      *(uint2v*)(orow + dm*16 + lg*4) = pkd;
    }
  }
}

// ---------------- launch ----------------
extern "C" void kernel_launch(void* const* d_in, const int* in_sizes, int n_in,
                              void* d_out, int out_size, void* d_ws, size_t ws_size,
                              hipStream_t stream)
{
  const float* x  = (const float*)d_in[0];
  const float* Wq = (const float*)d_in[1];
  const float* Wk = (const float*)d_in[2];
  const float* Wv = (const float*)d_in[3];
  const float* Wo = (const float*)d_in[4];
  const int* tpos = (const int*)d_in[5];

  char* w = (char*)d_ws;
  const size_t XBF = 16777216;   // 8192*1024*2
  const size_t WBF = 2097152;    // 1024*1024*2
  unsigned short* x_bf  = (unsigned short*)(w);
  unsigned short* wq_bf = (unsigned short*)(w + XBF);
  unsigned short* wo_bf = (unsigned short*)(w + XBF + 3*WBF);
  unsigned short* Qb  = (unsigned short*)(w + XBF + 4*WBF);
  unsigned short* Kb  = (unsigned short*)(w + XBF + 4*WBF + XBF);
  unsigned short* VTb = (unsigned short*)(w + XBF + 4*WBF + 2*XBF);
  unsigned short* Ab  = (unsigned short*)(w + XBF + 4*WBF + 3*XBF);

  cvt_f32_bf16<<<8192, 256, 0, stream>>>(x, x_bf, 2097152);
  cvt_weights<<<4096, 256, 0, stream>>>(Wq, Wk, Wv, Wo, wq_bf);

  // fused QKV projection + RoPE (N = 3072)
  gemm_gl<0><<<dim3(24, 64), 256, 0, stream>>>(x_bf, wq_bf, Qb, Kb, VTb, nullptr, tpos);

  flash_attn4<<<dim3(8, 64), 512, 0, stream>>>(Qb, Kb, VTb, Ab);

  // final O-projection -> fp32 d_out
  gemm_gl<1><<<dim3(8, 64), 256, 0, stream>>>(Ab, wo_bf, nullptr, nullptr, nullptr, (float*)d_out, tpos);
}

// Round 6
// 195.202 us; speedup vs baseline: 10.0962x; 1.0156x over previous
//
#include <hip/hip_runtime.h>
#include <stdint.h>

#define BATCH 4
#define SEQ 2048
#define DMODEL 1024
#define NHEADS 16
#define HDIM 64

typedef __attribute__((ext_vector_type(4))) short short4v;
typedef __attribute__((ext_vector_type(4))) float float4v;
typedef __attribute__((ext_vector_type(4))) int int4v;
typedef __attribute__((ext_vector_type(2))) unsigned int uint2v;
typedef __attribute__((ext_vector_type(4))) unsigned int uint4v;
typedef __attribute__((ext_vector_type(4))) unsigned short ushort4v;
typedef __attribute__((ext_vector_type(8))) __bf16 bf16x8;

union FragAB { short4v h[2]; unsigned int u[4]; bf16x8 v; };

// 0.125 * log2(e)  (folded into Q rope so softmax runs in exp2 domain)
#define QSCALE 0.18033688011112042f
// theta^(-2i/64) = 2^(-i * 2*log2(10000)/64)
#define ROPE_L2 -0.41524101186092030f

__device__ __forceinline__ float bf2f(unsigned short u){
  union { unsigned int i; float f; } v; v.i = ((unsigned int)u) << 16; return v.f;
}
__device__ __forceinline__ unsigned short f2bf(float f){
  union { unsigned int i; float f; } v; v.f = f;
  unsigned int x = v.i;
  return (unsigned short)((x + 0x7FFFu + ((x >> 16) & 1u)) >> 16);
}

// async global -> LDS, 16B per lane. LDS dest: wave-uniform base + lane*16.
__device__ __forceinline__ void gload16(const unsigned short* g, unsigned short* l){
  __builtin_amdgcn_global_load_lds(
      (const __attribute__((address_space(1))) void*)g,
      (__attribute__((address_space(3))) void*)l, 16, 0, 0);
}

// ---------------- fp32 -> bf16 conversion (vector x4) ----------------
__global__ void cvt_f32_bf16(const float* __restrict__ in, unsigned short* __restrict__ out, int n4){
  int i = blockIdx.x * 256 + threadIdx.x;
  if (i < n4){
    float4v f = ((const float4v*)in)[i];
    ushort4v o;
    o[0]=f2bf(f[0]); o[1]=f2bf(f[1]); o[2]=f2bf(f[2]); o[3]=f2bf(f[3]);
    ((ushort4v*)out)[i] = o;
  }
}

// all 4 weight matrices in one launch; out = 4 contiguous 1M-elt bf16 blocks
__global__ void cvt_weights(const float* __restrict__ Wq, const float* __restrict__ Wk,
                            const float* __restrict__ Wv, const float* __restrict__ Wo,
                            unsigned short* __restrict__ out){
  int idx = blockIdx.x * 256 + threadIdx.x;   // 4 * 262144
  int mat = idx >> 18;
  int i   = idx & 262143;
  const float* src = (mat == 0) ? Wq : (mat == 1) ? Wk : (mat == 2) ? Wv : Wo;
  float4v f = ((const float4v*)src)[i];
  ushort4v o;
  o[0]=f2bf(f[0]); o[1]=f2bf(f[1]); o[2]=f2bf(f[2]); o[3]=f2bf(f[3]);
  ((ushort4v*)(out + (size_t)mat * 1048576))[i] = o;
}

// ---------------- bf16 GEMM 128x128 tile, BK=32, 3-buffer counted-vmcnt pipeline ----
// C[m][n] = sum_k A[m][k]*W[n][k]
// MODE 0: fused QKV projection (N=3072) + RoPE on Q/K epilogue; V written as V^T.
// MODE 1: fp32 row-major Fd[m*DMODEL+n] (final O-projection).
// Raw s_barrier + counted s_waitcnt vmcnt(4): prefetched loads stay in flight
// across the barrier (T4); each wave issues exactly 4 gloads per stage.
template<int MODE>
__launch_bounds__(256, 3)
__global__ void gemm_cnt(const unsigned short* __restrict__ A,
                         const unsigned short* __restrict__ W,
                         unsigned short* __restrict__ Qd,
                         unsigned short* __restrict__ Kd,
                         unsigned short* __restrict__ Vd,
                         float* __restrict__ Fd,
                         const int* __restrict__ pos)
{
  __shared__ __align__(16) unsigned short Al[3][128][32];
  __shared__ __align__(16) unsigned short Bl[3][128][32];

  const int tid  = threadIdx.x;
  const int wid  = tid >> 6, lane = tid & 63;
  const int lg   = lane >> 4, lr = lane & 15;
  const int wm   = wid >> 1, wn = wid & 1;
  const int m0   = blockIdx.y * 128;
  const int n0   = blockIdx.x * 128;

  // staging: one gload covers 16 rows (64 lanes x 16B); lane l -> row +l/4, col (l&3)*8
  const unsigned short* Ab = A + (size_t)(m0 + wid*32 + (lane >> 2)) * DMODEL + (lane & 3) * 8;
  const unsigned short* Wb = W + (size_t)(n0 + wid*32 + (lane >> 2)) * DMODEL + (lane & 3) * 8;

  float4v acc[4][4] = {};
  const int nt = DMODEL / 32;   // 32

  // each wave: exactly 4 gloads per stage, uniform order
  #define STAGE_G(bufi, kofs) do{                                          \
    gload16(Ab + (kofs),                 &Al[bufi][wid*32][0]);             \
    gload16(Ab + (size_t)16*DMODEL + (kofs), &Al[bufi][wid*32 + 16][0]);    \
    gload16(Wb + (kofs),                 &Bl[bufi][wid*32][0]);             \
    gload16(Wb + (size_t)16*DMODEL + (kofs), &Bl[bufi][wid*32 + 16][0]);    \
  }while(0)

  STAGE_G(0, 0);
  STAGE_G(1, 32);

  int bc = 0;   // compute buffer = t % 3
  #pragma unroll 1
  for (int t = 0; t < nt; ++t){
    if (t < nt - 1) asm volatile("s_waitcnt vmcnt(4)" ::: "memory");
    else            asm volatile("s_waitcnt vmcnt(0)" ::: "memory");
    __builtin_amdgcn_s_barrier();

    if (t + 2 < nt){
      int bs = bc + 2; if (bs >= 3) bs -= 3;
      STAGE_G(bs, (t + 2) * 32);
    }

    FragAB afr[4], bfr[4];
    #pragma unroll
    for (int f = 0; f < 4; ++f){
      afr[f].v = *(const bf16x8*)&Al[bc][wm*64 + f*16 + lr][lg*8];
      bfr[f].v = *(const bf16x8*)&Bl[bc][wn*64 + f*16 + lr][lg*8];
    }
    #pragma unroll
    for (int fm = 0; fm < 4; ++fm)
      #pragma unroll
      for (int fn = 0; fn < 4; ++fn)
        acc[fm][fn] = __builtin_amdgcn_mfma_f32_16x16x32_bf16(afr[fm].v, bfr[fn].v, acc[fm][fn], 0, 0, 0);

    bc = (bc == 2) ? 0 : bc + 1;
  }
  #undef STAGE_G

  #pragma unroll
  for (int fm = 0; fm < 4; ++fm)
    #pragma unroll
    for (int fn = 0; fn < 4; ++fn){
      const int gm = m0 + wm*64 + fm*16 + lg*4;   // +r
      const int gn = n0 + wn*64 + fn*16 + lr;
      if (MODE == 1){
        float* op = Fd + (size_t)gm * DMODEL + gn;
        #pragma unroll
        for (int r = 0; r < 4; ++r) op[(size_t)r * DMODEL] = acc[fm][fn][r];
      } else {
        const int mat = gn >> 10;
        const int b = gm >> 11, s = gm & (SEQ - 1);
        const int h = (gn >> 6) & (NHEADS - 1), d = gn & (HDIM - 1);
        if (mat == 2){
          unsigned short* op = Vd + (((size_t)(b*NHEADS + h))*HDIM + d)*SEQ + s;
          uint2v pk2;
          pk2[0] = (unsigned int)f2bf(acc[fm][fn][0]) | ((unsigned int)f2bf(acc[fm][fn][1]) << 16);
          pk2[1] = (unsigned int)f2bf(acc[fm][fn][2]) | ((unsigned int)f2bf(acc[fm][fn][3]) << 16);
          *(uint2v*)op = pk2;
        } else {
          // fused RoPE: pair (d even, d odd) sits in lanes lr^1
          int4v p4v = *(const int4v*)(pos + s);
          const float invf = exp2f(ROPE_L2 * (float)(d >> 1));
          const float sgn  = (d & 1) ? 1.f : -1.f;
          const float scl  = (mat == 0) ? QSCALE : 1.0f;
          unsigned short* op = (mat == 0 ? Qd : Kd) + (((size_t)(b*NHEADS + h))*SEQ + s)*HDIM + d;
          #pragma unroll
          for (int r = 0; r < 4; ++r){
            float v  = acc[fm][fn][r];
            float pv = __shfl_xor(v, 1);
            float ang = (float)p4v[r] * invf;
            float sn, cs;
            __sincosf(ang, &sn, &cs);
            op[(size_t)r * HDIM] = f2bf((v*cs + pv*sn*sgn) * scl);
          }
        }
      }
    }
}

// ---------------- MFMA causal flash attention v4: 8 waves, 16 q-rows/wave ----------------
// grid (8, 64): block bx handles q-tile pair {15-bx, bx} (uniform 34 K-tiles).
// 512 threads = 8 waves; 2 blocks/CU -> 4 waves/SIMD for MFMA/VALU/trans overlap.
// S^T = mfma(K, Q); P stays in registers as B-frag of O^T = mfma(V^T, P).
__launch_bounds__(512, 4)
__global__ void flash_attn4(const unsigned short* __restrict__ Qg,
                            const unsigned short* __restrict__ Kg,
                            const unsigned short* __restrict__ VTg,
                            unsigned short* __restrict__ Og)
{
  __shared__ __align__(16) unsigned short Kl[2][64][72];
  __shared__ __align__(16) unsigned short Vt[2][64][72];

  const int tid  = threadIdx.x;
  const int w    = tid >> 6, lane = tid & 63;
  const int lg   = lane >> 4, lr = lane & 15;
  const int bx   = blockIdx.x;
  const int bh   = blockIdx.y;
  const size_t baseK = (size_t)bh * SEQ * HDIM;
  const size_t baseV = (size_t)bh * HDIM * SEQ;
  const int b = bh >> 4, h = bh & (NHEADS - 1);

  const int sr  = tid >> 3;        // 0..63
  const int sc8 = (tid & 7) * 8;   // 0..56

  #pragma unroll 1
  for (int ph = 0; ph < 2; ++ph){
    const int qtb   = ph ? bx : 15 - bx;
    const int q0    = qtb * 128;
    const int qmin  = q0 + w * 16;
    const int wlast = qmin >> 6;
    const int nt    = 2 * qtb + 2;
    const int qglob = qmin + lr;

    // Q frags (B operand), contiguous sigma: chunk c holds d = c*32 + lg*8 + j
    FragAB qf[2];
    {
      const unsigned short* qrow = Qg + baseK + (size_t)qglob * HDIM;
      qf[0].v = *(const bf16x8*)(qrow + lg*8);
      qf[1].v = *(const bf16x8*)(qrow + 32 + lg*8);
    }

    float4v o[4] = {};
    float mrun = -1e30f, lrun = 0.f;

    uint4v kreg, vreg;
    kreg = *(const uint4v*)(Kg  + baseK + (size_t)sr * HDIM + sc8);
    vreg = *(const uint4v*)(VTg + baseV + (size_t)sr * SEQ + sc8);
    *(uint4v*)&Kl[0][sr][sc8] = kreg;
    *(uint4v*)&Vt[0][sr][sc8] = vreg;
    __syncthreads();

    int buf = 0;
    for (int t = 0; t < nt; ++t){
      const int nxt = t + 1;
      if (nxt < nt){
        const int kv1 = nxt * 64;
        kreg = *(const uint4v*)(Kg  + baseK + (size_t)(kv1 + sr) * HDIM + sc8);
        vreg = *(const uint4v*)(VTg + baseV + (size_t)sr * SEQ + kv1 + sc8);
      }

      if (t <= wlast){
        const int kv0 = t * 64;
        const bool diag = (t == wlast);
        float p4[4][4];

        __builtin_amdgcn_s_setprio(1);
        #pragma unroll
        for (int kb = 0; kb < 4; ++kb){
          const unsigned short* krow = &Kl[buf][kb*16 + lr][0];
          FragAB kf0, kf1;
          kf0.v = *(const bf16x8*)(krow + lg*8);
          kf1.v = *(const bf16x8*)(krow + 32 + lg*8);
          float4v st = {};
          st = __builtin_amdgcn_mfma_f32_16x16x32_bf16(kf0.v, qf[0].v, st, 0, 0, 0);
          st = __builtin_amdgcn_mfma_f32_16x16x32_bf16(kf1.v, qf[1].v, st, 0, 0, 0);
          if (diag){
            #pragma unroll
            for (int r = 0; r < 4; ++r)
              p4[kb][r] = (kv0 + kb*16 + lg*4 + r <= qglob) ? st[r] : -1e30f;
          } else {
            #pragma unroll
            for (int r = 0; r < 4; ++r) p4[kb][r] = st[r];
          }
        }
        __builtin_amdgcn_s_setprio(0);

        float rmax = p4[0][0];
        #pragma unroll
        for (int kb = 0; kb < 4; ++kb)
          #pragma unroll
          for (int r = 0; r < 4; ++r) rmax = fmaxf(rmax, p4[kb][r]);
        rmax = fmaxf(rmax, __shfl_xor(rmax, 16));
        rmax = fmaxf(rmax, __shfl_xor(rmax, 32));

        if (__any(rmax > mrun + 11.5f)){   // defer-max, exp2 domain
          float mnew  = fmaxf(mrun, rmax);
          float alpha = exp2f(mrun - mnew);
          lrun *= alpha;
          #pragma unroll
          for (int dm = 0; dm < 4; ++dm)
            #pragma unroll
            for (int r = 0; r < 4; ++r) o[dm][r] *= alpha;
          mrun = mnew;
        }
        float rsum = 0.f;
        #pragma unroll
        for (int kb = 0; kb < 4; ++kb)
          #pragma unroll
          for (int r = 0; r < 4; ++r){
            float e = exp2f(p4[kb][r] - mrun);
            p4[kb][r] = e;
            rsum += e;
          }
        rsum += __shfl_xor(rsum, 16);
        rsum += __shfl_xor(rsum, 32);
        lrun += rsum;

        // P -> bf16 frags: pf[kc].h[0] = p4[2kc][j] (k=lg*4+j), h[1] = p4[2kc+1][j]
        FragAB pf[2];
        #pragma unroll
        for (int kc = 0; kc < 2; ++kc){
          unsigned int u0, u1, u2, u3;
          asm("v_cvt_pk_bf16_f32 %0, %1, %2" : "=v"(u0) : "v"(p4[2*kc][0]),   "v"(p4[2*kc][1]));
          asm("v_cvt_pk_bf16_f32 %0, %1, %2" : "=v"(u1) : "v"(p4[2*kc][2]),   "v"(p4[2*kc][3]));
          asm("v_cvt_pk_bf16_f32 %0, %1, %2" : "=v"(u2) : "v"(p4[2*kc+1][0]), "v"(p4[2*kc+1][1]));
          asm("v_cvt_pk_bf16_f32 %0, %1, %2" : "=v"(u3) : "v"(p4[2*kc+1][2]), "v"(p4[2*kc+1][3]));
          pf[kc].u[0] = u0; pf[kc].u[1] = u1; pf[kc].u[2] = u2; pf[kc].u[3] = u3;
        }

        __builtin_amdgcn_s_setprio(1);
        #pragma unroll
        for (int dm = 0; dm < 4; ++dm){
          const unsigned short* vrow = &Vt[buf][dm*16 + lr][0];
          #pragma unroll
          for (int kc = 0; kc < 2; ++kc){
            FragAB vf;   // split sigma matches pf construction
            vf.h[0] = *(const short4v*)(vrow + kc*32 + lg*4);
            vf.h[1] = *(const short4v*)(vrow + kc*32 + 16 + lg*4);
            o[dm] = __builtin_amdgcn_mfma_f32_16x16x32_bf16(vf.v, pf[kc].v, o[dm], 0, 0, 0);
          }
        }
        __builtin_amdgcn_s_setprio(0);
      }

      if (nxt < nt){
        *(uint4v*)&Kl[buf^1][sr][sc8] = kreg;
        *(uint4v*)&Vt[buf^1][sr][sc8] = vreg;
      }
      __syncthreads();
      buf ^= 1;
    }

    const float inv = 1.0f / lrun;
    unsigned short* orow = Og + ((size_t)(b*SEQ + qglob)) * DMODEL + h*HDIM;
    #pragma unroll
    for (int dm = 0; dm < 4; ++dm){
      uint2v pkd;
      pkd[0] = (unsigned int)f2bf(o[dm][0]*inv) | ((unsigned int)f2bf(o[dm][1]*inv) << 16);
      pkd[1] = (unsigned int)f2bf(o[dm][2]*inv) | ((unsigned int)f2bf(o[dm][3]*inv) << 16);
      *(uint2v*)(orow + dm*16 + lg*4) = pkd;
    }
  }
}

// ---------------- launch ----------------
extern "C" void kernel_launch(void* const* d_in, const int* in_sizes, int n_in,
                              void* d_out, int out_size, void* d_ws, size_t ws_size,
                              hipStream_t stream)
{
  const float* x  = (const float*)d_in[0];
  const float* Wq = (const float*)d_in[1];
  const float* Wk = (const float*)d_in[2];
  const float* Wv = (const float*)d_in[3];
  const float* Wo = (const float*)d_in[4];
  const int* tpos = (const int*)d_in[5];

  char* w = (char*)d_ws;
  const size_t XBF = 16777216;   // 8192*1024*2
  const size_t WBF = 2097152;    // 1024*1024*2
  unsigned short* x_bf  = (unsigned short*)(w);
  unsigned short* wq_bf = (unsigned short*)(w + XBF);
  unsigned short* wo_bf = (unsigned short*)(w + XBF + 3*WBF);
  unsigned short* Qb  = (unsigned short*)(w + XBF + 4*WBF);
  unsigned short* Kb  = (unsigned short*)(w + XBF + 4*WBF + XBF);
  unsigned short* VTb = (unsigned short*)(w + XBF + 4*WBF + 2*XBF);
  unsigned short* Ab  = (unsigned short*)(w + XBF + 4*WBF + 3*XBF);

  cvt_f32_bf16<<<8192, 256, 0, stream>>>(x, x_bf, 2097152);
  cvt_weights<<<4096, 256, 0, stream>>>(Wq, Wk, Wv, Wo, wq_bf);

  // fused QKV projection + RoPE (N = 3072)
  gemm_cnt<0><<<dim3(24, 64), 256, 0, stream>>>(x_bf, wq_bf, Qb, Kb, VTb, nullptr, tpos);

  flash_attn4<<<dim3(8, 64), 512, 0, stream>>>(Qb, Kb, VTb, Ab);

  // final O-projection -> fp32 d_out
  gemm_cnt<1><<<dim3(8, 64), 256, 0, stream>>>(Ab, wo_bf, nullptr, nullptr, nullptr, (float*)d_out, tpos);
}